// Round 2
// baseline (174.197 us; speedup 1.0000x reference)
//
#include <hip/hip_runtime.h>
#include <hip/hip_bf16.h>

#define NB 2
#define SEQ 2048
#define DM 384
#define NH 8
#define HD 48
#define QKVN 1152

typedef __hip_bfloat16 bf16;
typedef __attribute__((ext_vector_type(8))) short short8;
typedef __attribute__((ext_vector_type(4))) float float4v;
typedef __attribute__((ext_vector_type(16))) float f32x16;

static __device__ __forceinline__ float bf2f(bf16 v){ return __bfloat162float(v); }
static __device__ __forceinline__ float ldin(const void* p, size_t i, int isf){
    return isf ? ((const float*)p)[i] : bf2f(((const bf16*)p)[i]);
}
// fp32 -> bf16 bits, RNE
static __device__ __forceinline__ short f2b(float f){
    union { float f; unsigned u; } a; a.f = f;
    unsigned r = a.u + 0x7FFFu + ((a.u >> 16) & 1u);
    return (short)(r >> 16);
}
// packed fp32x2 -> bf16x2 (v_cvt_pk_bf16_f32)
static __device__ __forceinline__ unsigned pk2(float a, float b){
    union { __hip_bfloat162 h; unsigned u; } r;
    r.h = __float22bfloat162_rn(float2{a, b});
    return r.u;
}
static __device__ __forceinline__ short8 u4pack(unsigned w0, unsigned w1, unsigned w2, unsigned w3){
    union { unsigned u[4]; short8 s; } r; r.u[0]=w0; r.u[1]=w1; r.u[2]=w2; r.u[3]=w3; return r.s;
}
// per-block input dtype probe (0 = bf16, 1 = fp32); wave-uniform
static __device__ __forceinline__ int detect_isf(const void* x){
    const unsigned short* xb = (const unsigned short*)x;
    int l = threadIdx.x & 63;
    union { unsigned u; float f; } a; a.u = ((unsigned)xb[2*l]) << 16;
    float ab = fabsf(a.f);
    int good = (a.f == 0.0f) || (ab > 9.765625e-4f && ab < 1024.0f);
    unsigned long long m = __ballot(good);
    return (__popcll(m) >= 32) ? 0 : 1;
}

// ---------------- K_prep
// sections: [0,8) coords->f32 float4 copy | [8,776) xb | [776,1352) W^T | [1352,1359) misc
__global__ __launch_bounds__(256) void k_prep(const void* __restrict__ x,
    const void* __restrict__ coords,
    const void* __restrict__ Wqkv, const void* __restrict__ Wout,
    const void* __restrict__ bqkv, const void* __restrict__ bout,
    const void* __restrict__ Wdist, const void* __restrict__ bdist,
    float* __restrict__ cjf, short* __restrict__ xb,
    short* __restrict__ WqT, short* __restrict__ WoT,
    float* __restrict__ bqf, float* __restrict__ bof,
    float* __restrict__ wdf, float* __restrict__ bdf)
{
    const int isf = detect_isf(x);
    const int t = threadIdx.x;
    const int b = blockIdx.x;
    if (b < 8) {
        #pragma unroll
        for (int k = 0; k < 2; ++k) {
            int e = b*512 + k*256 + t;           // 0..4095 over (batch, j)
            int bb = e >> 11, jj = e & 2047;
            size_t gi = ((size_t)bb*SEQ + jj)*3;
            float4 cv;
            cv.x = ldin(coords, gi, isf);
            cv.y = ldin(coords, gi+1, isf);
            cv.z = ldin(coords, gi+2, isf);
            cv.w = 0.0f;
            ((float4*)cjf)[e] = cv;
        }
    } else if (b < 776) {
        size_t i = ((size_t)(b-8)*256 + t)*8;
        if (isf) {
            const float* xf = (const float*)x + i;
            short o[8];
            #pragma unroll
            for (int e = 0; e < 8; ++e) o[e] = f2b(xf[e]);
            *(int4*)(xb + i) = *(const int4*)o;
        } else {
            *(int4*)(xb + i) = *(const int4*)((const short*)x + i);
        }
    } else if (b < 1352) {
        int bb, NW; const void* W; short* WT;
        if (b < 1208) { bb = b - 776;  NW = QKVN; W = Wqkv; WT = WqT; }
        else          { bb = b - 1208; NW = DM;   W = Wout; WT = WoT; }
        int ntiles = NW >> 5;
        int kt = bb / ntiles, nt = bb % ntiles;
        int k0 = kt*32, n0 = nt*32;
        __shared__ float Ls[32][33];
        for (int idx = t; idx < 1024; idx += 256) {
            int r = idx >> 5, c = idx & 31;
            Ls[r][c] = ldin(W, (size_t)(k0+r)*NW + n0 + c, isf);
        }
        __syncthreads();
        for (int idx = t; idx < 1024; idx += 256) {
            int r2 = idx >> 5, c2 = idx & 31;
            WT[(size_t)(n0+r2)*DM + k0 + c2] = f2b(Ls[c2][r2]);
        }
    } else {
        int idx = (b - 1352)*256 + t;
        const float log2e = 1.4426950408889634f;
        if (idx < QKVN) bqf[idx] = ldin(bqkv, idx, isf);
        else if (idx < QKVN + DM) bof[idx - QKVN] = ldin(bout, idx - QKVN, isf);
        else if (idx < QKVN + DM + NH) wdf[idx - QKVN - DM] = ldin(Wdist, idx - QKVN - DM, isf)*log2e;
        else if (idx < QKVN + DM + 2*NH) bdf[idx - QKVN - DM - NH] = ldin(bdist, idx - QKVN - DM - NH, isf)*log2e;
    }
}

// ---------------- K1: MFMA GEMM qkv = xb @ Wqkv + b; scatter to 32x32x16 frag layouts
// qg3/kg3: [bh][t32(64)][dc(3)][hi(2)][tok(32)][e(8)]  elem = X[tok][dc*16 + hi*8 + e]
// vg3:     [bh][jt(64)][jc(2)]{ dt0:[hi][32 d][e8] , dt1:[hi][16 d][e8] } 1536 s/tile.
//          slot (hi,e) holds token j = jc*16 + (e&3) + 8*(e>>2) + 4*hi  (verified 32x32
//          C-row order) so PV's A-operand is the raw sacc register order — no cross-lane.
__global__ __launch_bounds__(256) void k_qkv(const short* __restrict__ xb,
    const short* __restrict__ WT, const float* __restrict__ bias,
    short* __restrict__ qg3, short* __restrict__ kg3, short* __restrict__ vg3)
{
    __shared__ __align__(16) short As[64*72];
    __shared__ __align__(16) short Bs[128*72];   // reused as epilogue buffer
    const int t = threadIdx.x;
    const int w = t >> 6, lane = t & 63, L = lane & 15, quad = lane >> 4;
    const int mt = blockIdx.x / 9, nt = blockIdx.x % 9;
    const int row0 = mt*64, col0 = nt*128;
    const int wm = w & 1, wn = w >> 1;
    float4v acc[2][4] = {};
    for (int k0 = 0; k0 < DM; k0 += 64) {
        __syncthreads();
        for (int c = t; c < 512; c += 256) {
            int row = c >> 3, k8 = c & 7;
            *(int4*)(&As[row*72 + k8*8]) = *(const int4*)(xb + (size_t)(row0+row)*DM + k0 + k8*8);
        }
        for (int c = t; c < 1024; c += 256) {
            int row = c >> 3, k8 = c & 7;
            *(int4*)(&Bs[row*72 + k8*8]) = *(const int4*)(WT + (size_t)(col0+row)*DM + k0 + k8*8);
        }
        __syncthreads();
        #pragma unroll
        for (int kc = 0; kc < 2; ++kc) {
            short8 a0 = *(const short8*)(&As[(32*wm + L)*72 + kc*32 + quad*8]);
            short8 a1 = *(const short8*)(&As[(32*wm + 16 + L)*72 + kc*32 + quad*8]);
            #pragma unroll
            for (int ni = 0; ni < 4; ++ni) {
                short8 bf = *(const short8*)(&Bs[(64*wn + 16*ni + L)*72 + kc*32 + quad*8]);
                acc[0][ni] = __builtin_amdgcn_mfma_f32_16x16x32_bf16(a0, bf, acc[0][ni], 0, 0, 0);
                acc[1][ni] = __builtin_amdgcn_mfma_f32_16x16x32_bf16(a1, bf, acc[1][ni], 0, 0, 0);
            }
        }
    }
    const int which = col0 / DM;     // uniform per block (0=q,1=k,2=v)
    const int cbase = col0 % DM;
    short* Ep = Bs;
    __syncthreads();
    if (which < 2) {
        // row-major Ep[64 tokens][136]
        #pragma unroll
        for (int mi = 0; mi < 2; ++mi)
            #pragma unroll
            for (int ni = 0; ni < 4; ++ni) {
                int col_l = 64*wn + 16*ni + L;
                float bv = bias[col0 + col_l];
                #pragma unroll
                for (int r = 0; r < 4; ++r) {
                    int row_l = 32*wm + 16*mi + quad*4 + r;
                    Ep[row_l*136 + col_l] = f2b(acc[mi][ni][r] + bv);
                }
            }
        __syncthreads();
        short* dst = which ? kg3 : qg3;
        for (int c = t; c < 1024; c += 256) {
            int row_l = c >> 4, col_l = (c & 15)*8;   // 8 consecutive d, one token
            int row_g = row0 + row_l;
            int bi = row_g >> 11, nn = row_g & (SEQ-1);
            int c2 = cbase + col_l;
            int hh = c2/HD, dh = c2%HD;
            int bh = bi*NH + hh;
            int dc = dh >> 4, hi = (dh >> 3) & 1;
            size_t dstoff = ((size_t)bh*64 + (nn>>5))*1536 + (size_t)((dc*2 + hi)*256 + (nn&31)*8);
            *(int4*)(dst + dstoff) = *(const int4*)(&Ep[row_l*136 + col_l]);
        }
    } else {
        // col-major Ep[128 cols][72 tokens]
        #pragma unroll
        for (int mi = 0; mi < 2; ++mi)
            #pragma unroll
            for (int ni = 0; ni < 4; ++ni) {
                int col_l = 64*wn + 16*ni + L;
                float bv = bias[col0 + col_l];
                #pragma unroll
                for (int r = 0; r < 4; ++r) {
                    int row_l = 32*wm + 16*mi + quad*4 + r;
                    Ep[col_l*72 + row_l] = f2b(acc[mi][ni][r] + bv);
                }
            }
        __syncthreads();
        for (int c = t; c < 1024; c += 256) {
            int col_l = c >> 3, row8 = (c & 7)*8;     // 8 consecutive tokens, one d
            int row_g = row0 + row8;
            int bi = row_g >> 11, nn = row_g & (SEQ-1);
            int c2 = cbase + col_l;
            int hh = c2/HD, dh = c2%HD;
            int bh = bi*NH + hh;
            int jt = nn >> 5, jc = (nn >> 4) & 1;
            int ehalf = ((nn >> 3) & 1)*4;            // e>>2 half of the slot
            int dt = dh >> 5, dp = dh & 31;           // d-tile 0: 32 cols, d-tile 1: 16 cols
            int hstride = dt ? 128 : 256;
            size_t base = ((size_t)bh*64 + jt)*1536 + (size_t)(jc*768 + dt*512 + dp*8 + ehalf);
            *(int2*)(vg3 + base)           = *(const int2*)(&Ep[col_l*72 + row8]);
            *(int2*)(vg3 + base + hstride) = *(const int2*)(&Ep[col_l*72 + row8 + 4]);
        }
    }
}

// ---------------- K2: flash attention, 64 i per block, fused distance bias
// 4 waves split the j-range (wave w: tiles 4s+w). Each wave: 2 i-tiles of 32 (i = lane&31),
// QK^T 3 pad-free K=16 MFMA per (i-tile, j-tile); sacc: col=lane=i, row-slot r -> 
// j = jb + (r&3) + 8*(r>>2) + 4*hi  (m74/m101 layout, matches the round-0 dBp math).
// dist computed in-register: ci from 3 VGPRs/lane (fixed), cj broadcast ds_read from a
// 32 KB LDS coords copy. PV: pa = sacc-order p via cvt_pk; V slot-permuted at prep time.
// Swizzle: XCD x owns heads {2x,2x+1} for all i -> K+V (784 KB) L2-resident, read 32x.
__global__ __launch_bounds__(256, 2) void k_attn(
    const short* __restrict__ qg3, const short* __restrict__ kg3, const short* __restrict__ vg3,
    const float* __restrict__ cjf, const float* __restrict__ wdf,
    const float* __restrict__ bdf, short* __restrict__ aob)
{
    __shared__ float4 cjs[2048];       // 32 KB: this batch's coords
    __shared__ float Ored[2][64*48];   // 24 KB
    __shared__ float Lred[2][64];
    const int t = threadIdx.x;
    const int w = t >> 6, lane = t & 63;
    const int li = lane & 31, hi = lane >> 5;
    const int lg = (blockIdx.x & 7)*64 + (blockIdx.x >> 3);   // 512 % 8 == 0: bijective
    const int bh = lg >> 5, it = lg & 31;
    const int bi = bh >> 3, hh = bh & 7;
    const int i0 = it*64;
    const float scale2 = 0.14433756729740643f * 1.4426950408889634f;
    const float wd = wdf[hh], bd = bdf[hh];     // pre-scaled by log2e

    // stage coords of this batch into LDS
    for (int c = t; c < 2048; c += 256)
        cjs[c] = ((const float4*)cjf)[(size_t)bi*2048 + c];
    // ci per lane, both i-tiles
    float cix[2], ciy[2], ciz[2];
    #pragma unroll
    for (int m = 0; m < 2; ++m) {
        float4 cv = ((const float4*)cjf)[(size_t)bi*2048 + i0 + m*32 + li];
        cix[m] = cv.x; ciy[m] = cv.y; ciz[m] = cv.z;
    }
    // Q fragments: 2 i-tiles x 3 d-chunks
    const short* qB = qg3 + ((size_t)bh*64 + it*2)*1536 + hi*256 + li*8;
    short8 qf[2][3];
    #pragma unroll
    for (int m = 0; m < 2; ++m)
        #pragma unroll
        for (int d = 0; d < 3; ++d)
            qf[m][d] = *(const short8*)(qB + m*1536 + d*512);
    __syncthreads();

    f32x16 aO0[2] = {}, aO1[2] = {};
    float rsum[2] = {};

    const short* kBp = kg3 + ((size_t)bh*64 + w)*1536 + hi*256 + li*8;
    const short* vBp = vg3 + ((size_t)bh*64 + w)*1536 + li*8;
    int jb = w*32 + hi*4;

    for (int s = 0; s < 16; ++s) {
        short8 kf0 = *(const short8*)(kBp);
        short8 kf1 = *(const short8*)(kBp + 512);
        short8 kf2 = *(const short8*)(kBp + 1024);
        short8 v00 = *(const short8*)(vBp + hi*256);            // jc0, d 0..31
        short8 v10 = *(const short8*)(vBp + 768 + hi*256);      // jc1, d 0..31
        short8 v01 = *(const short8*)(vBp + 512 + hi*128);      // jc0, d 32..47 (cols>=16 junk)
        short8 v11 = *(const short8*)(vBp + 1280 + hi*128);     // jc1, d 32..47
        f32x16 s0 = {}, s1 = {};
        s0 = __builtin_amdgcn_mfma_f32_32x32x16_bf16(kf0, qf[0][0], s0, 0, 0, 0);
        s1 = __builtin_amdgcn_mfma_f32_32x32x16_bf16(kf0, qf[1][0], s1, 0, 0, 0);
        s0 = __builtin_amdgcn_mfma_f32_32x32x16_bf16(kf1, qf[0][1], s0, 0, 0, 0);
        s1 = __builtin_amdgcn_mfma_f32_32x32x16_bf16(kf1, qf[1][1], s1, 0, 0, 0);
        s0 = __builtin_amdgcn_mfma_f32_32x32x16_bf16(kf2, qf[0][2], s0, 0, 0, 0);
        s1 = __builtin_amdgcn_mfma_f32_32x32x16_bf16(kf2, qf[1][2], s1, 0, 0, 0);
        unsigned pw0[8], pw1[8];
        #pragma unroll
        for (int rq = 0; rq < 4; ++rq) {
            float p0[4], p1[4];
            #pragma unroll
            for (int q = 0; q < 4; ++q) {
                float4 cj = cjs[jb + 8*rq + q];
                int r = 4*rq + q;
                float dx0 = cix[0]-cj.x, dy0 = ciy[0]-cj.y, dz0 = ciz[0]-cj.z;
                float dd0 = sqrtf(dx0*dx0 + dy0*dy0 + dz0*dz0);
                float dx1 = cix[1]-cj.x, dy1 = ciy[1]-cj.y, dz1 = ciz[1]-cj.z;
                float dd1 = sqrtf(dx1*dx1 + dy1*dy1 + dz1*dz1);
                p0[q] = __builtin_amdgcn_exp2f(fmaf(s0[r], scale2, fmaf(dd0, wd, bd)));
                p1[q] = __builtin_amdgcn_exp2f(fmaf(s1[r], scale2, fmaf(dd1, wd, bd)));
            }
            rsum[0] += (p0[0] + p0[1]) + (p0[2] + p0[3]);
            rsum[1] += (p1[0] + p1[1]) + (p1[2] + p1[3]);
            pw0[2*rq]   = pk2(p0[0], p0[1]);
            pw0[2*rq+1] = pk2(p0[2], p0[3]);
            pw1[2*rq]   = pk2(p1[0], p1[1]);
            pw1[2*rq+1] = pk2(p1[2], p1[3]);
        }
        short8 pa00 = u4pack(pw0[0], pw0[1], pw0[2], pw0[3]);   // tile0, j 0..15 slots
        short8 pa01 = u4pack(pw0[4], pw0[5], pw0[6], pw0[7]);   // tile0, j 16..31 slots
        short8 pa10 = u4pack(pw1[0], pw1[1], pw1[2], pw1[3]);
        short8 pa11 = u4pack(pw1[4], pw1[5], pw1[6], pw1[7]);
        aO0[0] = __builtin_amdgcn_mfma_f32_32x32x16_bf16(pa00, v00, aO0[0], 0, 0, 0);
        aO0[0] = __builtin_amdgcn_mfma_f32_32x32x16_bf16(pa01, v10, aO0[0], 0, 0, 0);
        aO1[0] = __builtin_amdgcn_mfma_f32_32x32x16_bf16(pa00, v01, aO1[0], 0, 0, 0);
        aO1[0] = __builtin_amdgcn_mfma_f32_32x32x16_bf16(pa01, v11, aO1[0], 0, 0, 0);
        aO0[1] = __builtin_amdgcn_mfma_f32_32x32x16_bf16(pa10, v00, aO0[1], 0, 0, 0);
        aO0[1] = __builtin_amdgcn_mfma_f32_32x32x16_bf16(pa11, v10, aO0[1], 0, 0, 0);
        aO1[1] = __builtin_amdgcn_mfma_f32_32x32x16_bf16(pa10, v01, aO1[1], 0, 0, 0);
        aO1[1] = __builtin_amdgcn_mfma_f32_32x32x16_bf16(pa11, v11, aO1[1], 0, 0, 0);
        kBp += 4*1536; vBp += 4*1536; jb += 128;
    }
    #pragma unroll
    for (int m = 0; m < 2; ++m)
        rsum[m] += __shfl_xor(rsum[m], 32);

    // cross-wave tree reduction
    if (w >= 2) {
        float* Od = Ored[w-2];
        #pragma unroll
        for (int m = 0; m < 2; ++m)
            #pragma unroll
            for (int r = 0; r < 16; ++r) {
                int ii = m*32 + (r & 3) + 8*(r >> 2) + 4*hi;
                Od[ii*48 + li] = aO0[m][r];
                if (li < 16) Od[ii*48 + 32 + li] = aO1[m][r];
            }
        if (lane < 32) { Lred[w-2][li] = rsum[0]; Lred[w-2][32 + li] = rsum[1]; }
    }
    __syncthreads();
    if (w < 2) {
        const float* Od = Ored[w];
        #pragma unroll
        for (int m = 0; m < 2; ++m)
            #pragma unroll
            for (int r = 0; r < 16; ++r) {
                int ii = m*32 + (r & 3) + 8*(r >> 2) + 4*hi;
                aO0[m][r] += Od[ii*48 + li];
                aO1[m][r] += Od[ii*48 + 32 + (li & 15)];
            }
        rsum[0] += Lred[w][li]; rsum[1] += Lred[w][32 + li];
    }
    __syncthreads();
    if (w == 1) {
        float* Od = Ored[0];
        #pragma unroll
        for (int m = 0; m < 2; ++m)
            #pragma unroll
            for (int r = 0; r < 16; ++r) {
                int ii = m*32 + (r & 3) + 8*(r >> 2) + 4*hi;
                Od[ii*48 + li] = aO0[m][r];
                if (li < 16) Od[ii*48 + 32 + li] = aO1[m][r];
            }
        if (lane < 32) { Lred[0][li] = rsum[0]; Lred[0][32 + li] = rsum[1]; }
    }
    __syncthreads();
    if (w == 0) {
        float* Od = Ored[0];
        #pragma unroll
        for (int m = 0; m < 2; ++m)
            #pragma unroll
            for (int r = 0; r < 16; ++r) {
                int ii = m*32 + (r & 3) + 8*(r >> 2) + 4*hi;
                Od[ii*48 + li] += aO0[m][r];
                if (li < 16) Od[ii*48 + 32 + li] += aO1[m][r];
            }
        if (lane < 32) { Lred[0][li] += rsum[0]; Lred[0][32 + li] += rsum[1]; }
    }
    __syncthreads();
    // all waves: normalize + coalesced int4 store of the 64x48 tile
    for (int c = t; c < 384; c += 256) {
        int r = c / 6, d8 = (c % 6)*8;
        float inv = 1.0f / Lred[0][r];
        const float* src = &Ored[0][r*48 + d8];
        short o[8];
        #pragma unroll
        for (int e = 0; e < 8; ++e) o[e] = f2b(src[e]*inv);
        *(int4*)(aob + ((size_t)(bi*SEQ) + i0 + r)*DM + hh*HD + d8) = *(const int4*)o;
    }
}

// ---------------- K3: MFMA GEMM out = aob @ Wout + b_out
__global__ __launch_bounds__(256) void k_out(const short* __restrict__ aob,
    const short* __restrict__ WT, const float* __restrict__ bias,
    void* __restrict__ out, const void* __restrict__ x)
{
    __shared__ __align__(16) short As[64*72];
    __shared__ __align__(16) short Bs[128*72];
    const int isf = detect_isf(x);
    const int t = threadIdx.x;
    const int w = t >> 6, lane = t & 63, L = lane & 15, quad = lane >> 4;
    const int mt = blockIdx.x / 3, nt = blockIdx.x % 3;
    const int row0 = mt*64, col0 = nt*128;
    const int wm = w & 1, wn = w >> 1;
    float4v acc[2][4] = {};
    for (int k0 = 0; k0 < DM; k0 += 64) {
        __syncthreads();
        for (int c = t; c < 512; c += 256) {
            int row = c >> 3, k8 = c & 7;
            *(int4*)(&As[row*72 + k8*8]) = *(const int4*)(aob + (size_t)(row0+row)*DM + k0 + k8*8);
        }
        for (int c = t; c < 1024; c += 256) {
            int row = c >> 3, k8 = c & 7;
            *(int4*)(&Bs[row*72 + k8*8]) = *(const int4*)(WT + (size_t)(col0+row)*DM + k0 + k8*8);
        }
        __syncthreads();
        #pragma unroll
        for (int kc = 0; kc < 2; ++kc) {
            short8 a0 = *(const short8*)(&As[(32*wm + L)*72 + kc*32 + quad*8]);
            short8 a1 = *(const short8*)(&As[(32*wm + 16 + L)*72 + kc*32 + quad*8]);
            #pragma unroll
            for (int ni = 0; ni < 4; ++ni) {
                short8 bf = *(const short8*)(&Bs[(64*wn + 16*ni + L)*72 + kc*32 + quad*8]);
                acc[0][ni] = __builtin_amdgcn_mfma_f32_16x16x32_bf16(a0, bf, acc[0][ni], 0, 0, 0);
                acc[1][ni] = __builtin_amdgcn_mfma_f32_16x16x32_bf16(a1, bf, acc[1][ni], 0, 0, 0);
            }
        }
    }
    #pragma unroll
    for (int mi = 0; mi < 2; ++mi) {
        #pragma unroll
        for (int ni = 0; ni < 4; ++ni) {
            int col_g = col0 + 64*wn + 16*ni + L;
            float bv = bias[col_g];
            #pragma unroll
            for (int r = 0; r < 4; ++r) {
                int row_g = row0 + 32*wm + 16*mi + quad*4 + r;
                size_t oi = (size_t)row_g*DM + col_g;
                float val = acc[mi][ni][r] + bv;
                if (isf) ((float*)out)[oi] = val;
                else     ((bf16*)out)[oi]  = __float2bfloat16(val);
            }
        }
    }
}

extern "C" void kernel_launch(void* const* d_in, const int* in_sizes, int n_in,
                              void* d_out, int out_size, void* d_ws, size_t ws_size,
                              hipStream_t stream) {
    const void* x      = d_in[0];
    const void* coords = d_in[1];
    const void* Wqkv   = d_in[2];
    const void* bqkv   = d_in[3];
    const void* Wdist  = d_in[4];
    const void* bdist  = d_in[5];
    const void* Wout   = d_in[6];
    const void* bout   = d_in[7];

    short* qg3   = (short*)d_ws;                       // 16*64*1536 = 1,572,864
    short* kg3   = qg3  + (size_t)1572864;
    short* vg3   = kg3  + (size_t)1572864;             // + 256 overread pad
    short* aob   = vg3  + (size_t)1573120;
    short* xb    = aob  + (size_t)1572864;
    short* WqT   = xb   + (size_t)1572864;
    short* WoT   = WqT  + (size_t)442368;
    float* bqf   = (float*)(WoT + (size_t)147456);     // 16B-aligned (offset 16,908,800 B)
    float* bof   = bqf + QKVN;
    float* wdf   = bof + DM;
    float* bdf   = wdf + NH;
    float* cjf   = bdf + NH;                           // 2*2048*4 floats, 16B-aligned

    k_prep<<<dim3(1359), dim3(256), 0, stream>>>(x, coords, Wqkv, Wout, bqkv, bout,
                                                 Wdist, bdist, cjf, xb, WqT, WoT,
                                                 bqf, bof, wdf, bdf);
    k_qkv<<<dim3(64*9), dim3(256), 0, stream>>>(xb, WqT, bqf, qg3, kg3, vg3);
    k_attn<<<dim3(512), dim3(256), 0, stream>>>(qg3, kg3, vg3, cjf, wdf, bdf, aob);
    k_out<<<dim3(64*3), dim3(256), 0, stream>>>(aob, WoT, bof, d_out, x);
}

// Round 3
// 162.175 us; speedup vs baseline: 1.0741x; 1.0741x over previous
//
#include <hip/hip_runtime.h>
#include <hip/hip_bf16.h>

#define NB 2
#define SEQ 2048
#define DM 384
#define NH 8
#define HD 48
#define QKVN 1152

typedef __hip_bfloat16 bf16;
typedef __attribute__((ext_vector_type(8))) short short8;
typedef __attribute__((ext_vector_type(4))) float float4v;
typedef __attribute__((ext_vector_type(16))) float f32x16;

static __device__ __forceinline__ float bf2f(bf16 v){ return __bfloat162float(v); }
static __device__ __forceinline__ float ldin(const void* p, size_t i, int isf){
    return isf ? ((const float*)p)[i] : bf2f(((const bf16*)p)[i]);
}
// fp32 -> bf16 bits, RNE
static __device__ __forceinline__ short f2b(float f){
    union { float f; unsigned u; } a; a.f = f;
    unsigned r = a.u + 0x7FFFu + ((a.u >> 16) & 1u);
    return (short)(r >> 16);
}
// packed fp32x2 -> bf16x2 (v_cvt_pk_bf16_f32)
static __device__ __forceinline__ unsigned pk2(float a, float b){
    union { __hip_bfloat162 h; unsigned u; } r;
    r.h = __float22bfloat162_rn(float2{a, b});
    return r.u;
}
static __device__ __forceinline__ float bflo(unsigned u){
    union { unsigned u; float f; } a; a.u = u << 16; return a.f;
}
static __device__ __forceinline__ float bfhi(unsigned u){
    union { unsigned u; float f; } a; a.u = u & 0xFFFF0000u; return a.f;
}
static __device__ __forceinline__ short8 u4pack(unsigned w0, unsigned w1, unsigned w2, unsigned w3){
    union { unsigned u[4]; short8 s; } r; r.u[0]=w0; r.u[1]=w1; r.u[2]=w2; r.u[3]=w3; return r.s;
}
// per-block input dtype probe (0 = bf16, 1 = fp32); wave-uniform
static __device__ __forceinline__ int detect_isf(const void* x){
    const unsigned short* xb = (const unsigned short*)x;
    int l = threadIdx.x & 63;
    union { unsigned u; float f; } a; a.u = ((unsigned)xb[2*l]) << 16;
    float ab = fabsf(a.f);
    int good = (a.f == 0.0f) || (ab > 9.765625e-4f && ab < 1024.0f);
    unsigned long long m = __ballot(good);
    return (__popcll(m) >= 32) ? 0 : 1;
}

// ---------------- K_prep
// sections: [0,512) dist8 | [512,1088) W^T | [1088,1095) misc
// dist8 layout: [b][jg = j>>2 (512)][i(2048)][jj(4)] bf16
// (dist precompute is shared across the 8 heads: 8.4M sqrts once, vs 67M if fused into
//  k_attn — round-2 measured that fusion makes k_attn trans-pipe-bound, 73.7 us.)
__global__ __launch_bounds__(256) void k_prep(const void* __restrict__ x,
    const void* __restrict__ coords,
    const void* __restrict__ Wqkv, const void* __restrict__ Wout,
    const void* __restrict__ bqkv, const void* __restrict__ bout,
    const void* __restrict__ Wdist, const void* __restrict__ bdist,
    short* __restrict__ dist8,
    short* __restrict__ WqT, short* __restrict__ WoT,
    float* __restrict__ bqf, float* __restrict__ bof,
    float* __restrict__ wdf, float* __restrict__ bdf)
{
    const int isf = detect_isf(x);
    const int t = threadIdx.x;
    const int b = blockIdx.x;
    if (b < 512) {
        const int bb = b >> 8;               // batch
        const int jg = (b >> 1) & 127;       // 16-j group
        const int j0 = jg * 16;
        const int ih = (b & 1) * 1024;       // i-half
        __shared__ float cjx[16], cjy[16], cjz[16];
        if (t < 16) {
            int gj = (bb*SEQ + j0 + t)*3;
            cjx[t] = ldin(coords, gj, isf);
            cjy[t] = ldin(coords, gj+1, isf);
            cjz[t] = ldin(coords, gj+2, isf);
        }
        __syncthreads();
        #pragma unroll
        for (int k = 0; k < 4; ++k) {
            int i = ih + k*256 + t;
            int gi = (bb*SEQ + i)*3;
            float px = ldin(coords, gi, isf), py = ldin(coords, gi+1, isf), pz = ldin(coords, gi+2, isf);
            short o[16];
            #pragma unroll
            for (int e = 0; e < 16; ++e) {
                float dx = px - cjx[e], dy = py - cjy[e], dz = pz - cjz[e];
                o[e] = f2b(sqrtf(dx*dx + dy*dy + dz*dz));
            }
            // 4 groups of 4 j each: [b][jg*4+g][i][4]
            short* dst = dist8 + (((size_t)bb*512 + (size_t)jg*4)*SEQ + i)*4;
            *(int2*)(dst)          = *(const int2*)(o);
            *(int2*)(dst + SEQ*4)  = *(const int2*)(o + 4);
            *(int2*)(dst + SEQ*8)  = *(const int2*)(o + 8);
            *(int2*)(dst + SEQ*12) = *(const int2*)(o + 12);
        }
    } else if (b < 1088) {
        int bb, NW; const void* W; short* WT;
        if (b < 944) { bb = b - 512; NW = QKVN; W = Wqkv; WT = WqT; }
        else         { bb = b - 944; NW = DM;   W = Wout; WT = WoT; }
        int ntiles = NW >> 5;
        int kt = bb / ntiles, nt = bb % ntiles;
        int k0 = kt*32, n0 = nt*32;
        __shared__ float Ls[32][33];
        for (int idx = t; idx < 1024; idx += 256) {
            int r = idx >> 5, c = idx & 31;
            Ls[r][c] = ldin(W, (size_t)(k0+r)*NW + n0 + c, isf);
        }
        __syncthreads();
        for (int idx = t; idx < 1024; idx += 256) {
            int r2 = idx >> 5, c2 = idx & 31;
            WT[(size_t)(n0+r2)*DM + k0 + c2] = f2b(Ls[c2][r2]);
        }
    } else {
        int idx = (b - 1088)*256 + t;
        const float log2e = 1.4426950408889634f;
        if (idx < QKVN) bqf[idx] = ldin(bqkv, idx, isf);
        else if (idx < QKVN + DM) bof[idx - QKVN] = ldin(bout, idx - QKVN, isf);
        else if (idx < QKVN + DM + NH) wdf[idx - QKVN - DM] = ldin(Wdist, idx - QKVN - DM, isf)*log2e;
        else if (idx < QKVN + DM + 2*NH) bdf[idx - QKVN - DM - NH] = ldin(bdist, idx - QKVN - DM - NH, isf)*log2e;
    }
}

// ---------------- K1: MFMA GEMM qkv = x @ Wqkv + b; scatter to 32x32x16 frag layouts
// (x read directly, converted to bf16 during As staging — no xb staging pass.)
// qg3/kg3: [bh][t32(64)][dc(3)][hi(2)][tok(32)][e(8)]  elem = X[tok][dc*16 + hi*8 + e]
// vg3:     [bh][jt(64)][jc(2)]{ dt0:[hi][32 d][e8] , dt1:[hi][16 d][e8] } 1536 s/tile.
//          slot (hi,e) holds token j = jc*16 + (e&3) + 8*(e>>2) + 4*hi  (verified 32x32
//          C-row order) so PV's A-operand is the raw sacc register order — no cross-lane.
__global__ __launch_bounds__(256) void k_qkv(const void* __restrict__ x,
    const short* __restrict__ WT, const float* __restrict__ bias,
    short* __restrict__ qg3, short* __restrict__ kg3, short* __restrict__ vg3)
{
    __shared__ __align__(16) short As[64*72];
    __shared__ __align__(16) short Bs[128*72];   // reused as epilogue buffer
    const int isf = detect_isf(x);
    const int t = threadIdx.x;
    const int w = t >> 6, lane = t & 63, L = lane & 15, quad = lane >> 4;
    const int mt = blockIdx.x / 9, nt = blockIdx.x % 9;
    const int row0 = mt*64, col0 = nt*128;
    const int wm = w & 1, wn = w >> 1;
    float4v acc[2][4] = {};
    for (int k0 = 0; k0 < DM; k0 += 64) {
        __syncthreads();
        for (int c = t; c < 512; c += 256) {
            int row = c >> 3, k8 = c & 7;
            size_t src = (size_t)(row0+row)*DM + k0 + k8*8;
            if (isf) {
                const float* xf = (const float*)x + src;
                short o[8];
                #pragma unroll
                for (int e = 0; e < 8; ++e) o[e] = f2b(xf[e]);
                *(int4*)(&As[row*72 + k8*8]) = *(const int4*)o;
            } else {
                *(int4*)(&As[row*72 + k8*8]) = *(const int4*)((const short*)x + src);
            }
        }
        for (int c = t; c < 1024; c += 256) {
            int row = c >> 3, k8 = c & 7;
            *(int4*)(&Bs[row*72 + k8*8]) = *(const int4*)(WT + (size_t)(col0+row)*DM + k0 + k8*8);
        }
        __syncthreads();
        #pragma unroll
        for (int kc = 0; kc < 2; ++kc) {
            short8 a0 = *(const short8*)(&As[(32*wm + L)*72 + kc*32 + quad*8]);
            short8 a1 = *(const short8*)(&As[(32*wm + 16 + L)*72 + kc*32 + quad*8]);
            #pragma unroll
            for (int ni = 0; ni < 4; ++ni) {
                short8 bf = *(const short8*)(&Bs[(64*wn + 16*ni + L)*72 + kc*32 + quad*8]);
                acc[0][ni] = __builtin_amdgcn_mfma_f32_16x16x32_bf16(a0, bf, acc[0][ni], 0, 0, 0);
                acc[1][ni] = __builtin_amdgcn_mfma_f32_16x16x32_bf16(a1, bf, acc[1][ni], 0, 0, 0);
            }
        }
    }
    const int which = col0 / DM;     // uniform per block (0=q,1=k,2=v)
    const int cbase = col0 % DM;
    short* Ep = Bs;
    __syncthreads();
    if (which < 2) {
        // row-major Ep[64 tokens][136]
        #pragma unroll
        for (int mi = 0; mi < 2; ++mi)
            #pragma unroll
            for (int ni = 0; ni < 4; ++ni) {
                int col_l = 64*wn + 16*ni + L;
                float bv = bias[col0 + col_l];
                #pragma unroll
                for (int r = 0; r < 4; ++r) {
                    int row_l = 32*wm + 16*mi + quad*4 + r;
                    Ep[row_l*136 + col_l] = f2b(acc[mi][ni][r] + bv);
                }
            }
        __syncthreads();
        short* dst = which ? kg3 : qg3;
        for (int c = t; c < 1024; c += 256) {
            int row_l = c >> 4, col_l = (c & 15)*8;   // 8 consecutive d, one token
            int row_g = row0 + row_l;
            int bi = row_g >> 11, nn = row_g & (SEQ-1);
            int c2 = cbase + col_l;
            int hh = c2/HD, dh = c2%HD;
            int bh = bi*NH + hh;
            int dc = dh >> 4, hi = (dh >> 3) & 1;
            size_t dstoff = ((size_t)bh*64 + (nn>>5))*1536 + (size_t)((dc*2 + hi)*256 + (nn&31)*8);
            *(int4*)(dst + dstoff) = *(const int4*)(&Ep[row_l*136 + col_l]);
        }
    } else {
        // col-major Ep[128 cols][72 tokens]
        #pragma unroll
        for (int mi = 0; mi < 2; ++mi)
            #pragma unroll
            for (int ni = 0; ni < 4; ++ni) {
                int col_l = 64*wn + 16*ni + L;
                float bv = bias[col0 + col_l];
                #pragma unroll
                for (int r = 0; r < 4; ++r) {
                    int row_l = 32*wm + 16*mi + quad*4 + r;
                    Ep[col_l*72 + row_l] = f2b(acc[mi][ni][r] + bv);
                }
            }
        __syncthreads();
        for (int c = t; c < 1024; c += 256) {
            int col_l = c >> 3, row8 = (c & 7)*8;     // 8 consecutive tokens, one d
            int row_g = row0 + row8;
            int bi = row_g >> 11, nn = row_g & (SEQ-1);
            int c2 = cbase + col_l;
            int hh = c2/HD, dh = c2%HD;
            int bh = bi*NH + hh;
            int jt = nn >> 5, jc = (nn >> 4) & 1;
            int ehalf = ((nn >> 3) & 1)*4;            // e>>2 half of the slot
            int dt = dh >> 5, dp = dh & 31;           // d-tile 0: 32 cols, d-tile 1: 16 cols
            int hstride = dt ? 128 : 256;
            size_t base = ((size_t)bh*64 + jt)*1536 + (size_t)(jc*768 + dt*512 + dp*8 + ehalf);
            *(int2*)(vg3 + base)           = *(const int2*)(&Ep[col_l*72 + row8]);
            *(int2*)(vg3 + base + hstride) = *(const int2*)(&Ep[col_l*72 + row8 + 4]);
        }
    }
}

// ---------------- K2: flash attention, 64 i per block, dist8 bias loaded (bf16)
// 4 waves split the j-range (wave w: tiles 4s+w). Each wave: 2 i-tiles of 32 (i = lane&31),
// QK^T 3 pad-free K=16 MFMA per (i-tile, j-tile); sacc: col=lane=i, row-slot r ->
// j = w*32 + 128*s + (r&3) + 8*(r>>2) + 4*hi  (m74/m101 layout).
// PV: pa = sacc-order p via cvt_pk; V slot-permuted at prep time. 14 MFMA per iter.
// Swizzle: XCD x owns heads {2x,2x+1} for all i -> K+V (784 KB) L2-resident, read 32x.
__global__ __launch_bounds__(256, 2) void k_attn(
    const short* __restrict__ qg3, const short* __restrict__ kg3, const short* __restrict__ vg3,
    const short* __restrict__ dist8, const float* __restrict__ wdf,
    const float* __restrict__ bdf, short* __restrict__ aob)
{
    __shared__ float Ored[2][64*48];   // 24 KB
    __shared__ float Lred[2][64];
    const int t = threadIdx.x;
    const int w = t >> 6, lane = t & 63;
    const int li = lane & 31, hi = lane >> 5;
    const int lg = (blockIdx.x & 7)*64 + (blockIdx.x >> 3);   // 512 % 8 == 0: bijective
    const int bh = lg >> 5, it = lg & 31;
    const int bi = bh >> 3, hh = bh & 7;
    const int i0 = it*64;
    const float scale2 = 0.14433756729740643f * 1.4426950408889634f;
    const float wd = wdf[hh], bd = bdf[hh];     // pre-scaled by log2e

    // Q fragments: 2 i-tiles x 3 d-chunks
    const short* qB = qg3 + ((size_t)bh*64 + it*2)*1536 + hi*256 + li*8;
    short8 qf[2][3];
    #pragma unroll
    for (int m = 0; m < 2; ++m)
        #pragma unroll
        for (int d = 0; d < 3; ++d)
            qf[m][d] = *(const short8*)(qB + m*1536 + d*512);

    f32x16 aO0[2] = {}, aO1[2] = {};
    float rsum[2] = {};

    const short* kBp = kg3 + ((size_t)bh*64 + w)*1536 + hi*256 + li*8;
    const short* vBp = vg3 + ((size_t)bh*64 + w)*1536 + li*8;
    // dist8: [bi][jg][i][jj4]; this wave's slot (rq,q,m): jg = w*8 + hi + 2*rq + 32*s,
    // i = i0 + m*32 + li, jj = q
    const short* dBp = dist8 + (((size_t)bi*512 + (size_t)w*8 + hi)*SEQ + i0 + li)*4;

    for (int s = 0; s < 16; ++s) {
        short8 kf0 = *(const short8*)(kBp);
        short8 kf1 = *(const short8*)(kBp + 512);
        short8 kf2 = *(const short8*)(kBp + 1024);
        short8 v00 = *(const short8*)(vBp + hi*256);            // jc0, d 0..31
        short8 v10 = *(const short8*)(vBp + 768 + hi*256);      // jc1, d 0..31
        short8 v01 = *(const short8*)(vBp + 512 + hi*128);      // jc0, d 32..47 (cols>=16 junk)
        short8 v11 = *(const short8*)(vBp + 1280 + hi*128);     // jc1, d 32..47
        f32x16 s0 = {}, s1 = {};
        s0 = __builtin_amdgcn_mfma_f32_32x32x16_bf16(kf0, qf[0][0], s0, 0, 0, 0);
        s1 = __builtin_amdgcn_mfma_f32_32x32x16_bf16(kf0, qf[1][0], s1, 0, 0, 0);
        s0 = __builtin_amdgcn_mfma_f32_32x32x16_bf16(kf1, qf[0][1], s0, 0, 0, 0);
        s1 = __builtin_amdgcn_mfma_f32_32x32x16_bf16(kf1, qf[1][1], s1, 0, 0, 0);
        s0 = __builtin_amdgcn_mfma_f32_32x32x16_bf16(kf2, qf[0][2], s0, 0, 0, 0);
        s1 = __builtin_amdgcn_mfma_f32_32x32x16_bf16(kf2, qf[1][2], s1, 0, 0, 0);
        unsigned pw0[8], pw1[8];
        #pragma unroll
        for (int rq = 0; rq < 4; ++rq) {
            int2 du0 = *(const int2*)(dBp + (size_t)SEQ*8*rq);          // i-tile 0
            int2 du1 = *(const int2*)(dBp + 128 + (size_t)SEQ*8*rq);    // i-tile 1
            float p0[4], p1[4];
            float a0 = bflo((unsigned)du0.x), a1 = bfhi((unsigned)du0.x);
            float a2 = bflo((unsigned)du0.y), a3 = bfhi((unsigned)du0.y);
            float b0 = bflo((unsigned)du1.x), b1 = bfhi((unsigned)du1.x);
            float b2 = bflo((unsigned)du1.y), b3 = bfhi((unsigned)du1.y);
            p0[0] = __builtin_amdgcn_exp2f(fmaf(s0[4*rq+0], scale2, fmaf(a0, wd, bd)));
            p0[1] = __builtin_amdgcn_exp2f(fmaf(s0[4*rq+1], scale2, fmaf(a1, wd, bd)));
            p0[2] = __builtin_amdgcn_exp2f(fmaf(s0[4*rq+2], scale2, fmaf(a2, wd, bd)));
            p0[3] = __builtin_amdgcn_exp2f(fmaf(s0[4*rq+3], scale2, fmaf(a3, wd, bd)));
            p1[0] = __builtin_amdgcn_exp2f(fmaf(s1[4*rq+0], scale2, fmaf(b0, wd, bd)));
            p1[1] = __builtin_amdgcn_exp2f(fmaf(s1[4*rq+1], scale2, fmaf(b1, wd, bd)));
            p1[2] = __builtin_amdgcn_exp2f(fmaf(s1[4*rq+2], scale2, fmaf(b2, wd, bd)));
            p1[3] = __builtin_amdgcn_exp2f(fmaf(s1[4*rq+3], scale2, fmaf(b3, wd, bd)));
            rsum[0] += (p0[0] + p0[1]) + (p0[2] + p0[3]);
            rsum[1] += (p1[0] + p1[1]) + (p1[2] + p1[3]);
            pw0[2*rq]   = pk2(p0[0], p0[1]);
            pw0[2*rq+1] = pk2(p0[2], p0[3]);
            pw1[2*rq]   = pk2(p1[0], p1[1]);
            pw1[2*rq+1] = pk2(p1[2], p1[3]);
        }
        short8 pa00 = u4pack(pw0[0], pw0[1], pw0[2], pw0[3]);   // tile0, j slots 0..15
        short8 pa01 = u4pack(pw0[4], pw0[5], pw0[6], pw0[7]);   // tile0, j slots 16..31
        short8 pa10 = u4pack(pw1[0], pw1[1], pw1[2], pw1[3]);
        short8 pa11 = u4pack(pw1[4], pw1[5], pw1[6], pw1[7]);
        aO0[0] = __builtin_amdgcn_mfma_f32_32x32x16_bf16(pa00, v00, aO0[0], 0, 0, 0);
        aO0[0] = __builtin_amdgcn_mfma_f32_32x32x16_bf16(pa01, v10, aO0[0], 0, 0, 0);
        aO1[0] = __builtin_amdgcn_mfma_f32_32x32x16_bf16(pa00, v01, aO1[0], 0, 0, 0);
        aO1[0] = __builtin_amdgcn_mfma_f32_32x32x16_bf16(pa01, v11, aO1[0], 0, 0, 0);
        aO0[1] = __builtin_amdgcn_mfma_f32_32x32x16_bf16(pa10, v00, aO0[1], 0, 0, 0);
        aO0[1] = __builtin_amdgcn_mfma_f32_32x32x16_bf16(pa11, v10, aO0[1], 0, 0, 0);
        aO1[1] = __builtin_amdgcn_mfma_f32_32x32x16_bf16(pa10, v01, aO1[1], 0, 0, 0);
        aO1[1] = __builtin_amdgcn_mfma_f32_32x32x16_bf16(pa11, v11, aO1[1], 0, 0, 0);
        kBp += 4*1536; vBp += 4*1536; dBp += (size_t)SEQ*128;
    }
    #pragma unroll
    for (int m = 0; m < 2; ++m)
        rsum[m] += __shfl_xor(rsum[m], 32);

    // cross-wave tree reduction
    if (w >= 2) {
        float* Od = Ored[w-2];
        #pragma unroll
        for (int m = 0; m < 2; ++m)
            #pragma unroll
            for (int r = 0; r < 16; ++r) {
                int ii = m*32 + (r & 3) + 8*(r >> 2) + 4*hi;
                Od[ii*48 + li] = aO0[m][r];
                if (li < 16) Od[ii*48 + 32 + li] = aO1[m][r];
            }
        if (lane < 32) { Lred[w-2][li] = rsum[0]; Lred[w-2][32 + li] = rsum[1]; }
    }
    __syncthreads();
    if (w < 2) {
        const float* Od = Ored[w];
        #pragma unroll
        for (int m = 0; m < 2; ++m)
            #pragma unroll
            for (int r = 0; r < 16; ++r) {
                int ii = m*32 + (r & 3) + 8*(r >> 2) + 4*hi;
                aO0[m][r] += Od[ii*48 + li];
                aO1[m][r] += Od[ii*48 + 32 + (li & 15)];
            }
        rsum[0] += Lred[w][li]; rsum[1] += Lred[w][32 + li];
    }
    __syncthreads();
    if (w == 1) {
        float* Od = Ored[0];
        #pragma unroll
        for (int m = 0; m < 2; ++m)
            #pragma unroll
            for (int r = 0; r < 16; ++r) {
                int ii = m*32 + (r & 3) + 8*(r >> 2) + 4*hi;
                Od[ii*48 + li] = aO0[m][r];
                if (li < 16) Od[ii*48 + 32 + li] = aO1[m][r];
            }
        if (lane < 32) { Lred[0][li] = rsum[0]; Lred[0][32 + li] = rsum[1]; }
    }
    __syncthreads();
    if (w == 0) {
        float* Od = Ored[0];
        #pragma unroll
        for (int m = 0; m < 2; ++m)
            #pragma unroll
            for (int r = 0; r < 16; ++r) {
                int ii = m*32 + (r & 3) + 8*(r >> 2) + 4*hi;
                Od[ii*48 + li] += aO0[m][r];
                if (li < 16) Od[ii*48 + 32 + li] += aO1[m][r];
            }
        if (lane < 32) { Lred[0][li] += rsum[0]; Lred[0][32 + li] += rsum[1]; }
    }
    __syncthreads();
    // all waves: normalize + coalesced int4 store of the 64x48 tile
    for (int c = t; c < 384; c += 256) {
        int r = c / 6, d8 = (c % 6)*8;
        float inv = 1.0f / Lred[0][r];
        const float* src = &Ored[0][r*48 + d8];
        short o[8];
        #pragma unroll
        for (int e = 0; e < 8; ++e) o[e] = f2b(src[e]*inv);
        *(int4*)(aob + ((size_t)(bi*SEQ) + i0 + r)*DM + hh*HD + d8) = *(const int4*)o;
    }
}

// ---------------- K3: MFMA GEMM out = aob @ Wout + b_out
__global__ __launch_bounds__(256) void k_out(const short* __restrict__ aob,
    const short* __restrict__ WT, const float* __restrict__ bias,
    void* __restrict__ out, const void* __restrict__ x)
{
    __shared__ __align__(16) short As[64*72];
    __shared__ __align__(16) short Bs[128*72];
    const int isf = detect_isf(x);
    const int t = threadIdx.x;
    const int w = t >> 6, lane = t & 63, L = lane & 15, quad = lane >> 4;
    const int mt = blockIdx.x / 3, nt = blockIdx.x % 3;
    const int row0 = mt*64, col0 = nt*128;
    const int wm = w & 1, wn = w >> 1;
    float4v acc[2][4] = {};
    for (int k0 = 0; k0 < DM; k0 += 64) {
        __syncthreads();
        for (int c = t; c < 512; c += 256) {
            int row = c >> 3, k8 = c & 7;
            *(int4*)(&As[row*72 + k8*8]) = *(const int4*)(aob + (size_t)(row0+row)*DM + k0 + k8*8);
        }
        for (int c = t; c < 1024; c += 256) {
            int row = c >> 3, k8 = c & 7;
            *(int4*)(&Bs[row*72 + k8*8]) = *(const int4*)(WT + (size_t)(col0+row)*DM + k0 + k8*8);
        }
        __syncthreads();
        #pragma unroll
        for (int kc = 0; kc < 2; ++kc) {
            short8 a0 = *(const short8*)(&As[(32*wm + L)*72 + kc*32 + quad*8]);
            short8 a1 = *(const short8*)(&As[(32*wm + 16 + L)*72 + kc*32 + quad*8]);
            #pragma unroll
            for (int ni = 0; ni < 4; ++ni) {
                short8 bf = *(const short8*)(&Bs[(64*wn + 16*ni + L)*72 + kc*32 + quad*8]);
                acc[0][ni] = __builtin_amdgcn_mfma_f32_16x16x32_bf16(a0, bf, acc[0][ni], 0, 0, 0);
                acc[1][ni] = __builtin_amdgcn_mfma_f32_16x16x32_bf16(a1, bf, acc[1][ni], 0, 0, 0);
            }
        }
    }
    #pragma unroll
    for (int mi = 0; mi < 2; ++mi) {
        #pragma unroll
        for (int ni = 0; ni < 4; ++ni) {
            int col_g = col0 + 64*wn + 16*ni + L;
            float bv = bias[col_g];
            #pragma unroll
            for (int r = 0; r < 4; ++r) {
                int row_g = row0 + 32*wm + 16*mi + quad*4 + r;
                size_t oi = (size_t)row_g*DM + col_g;
                float val = acc[mi][ni][r] + bv;
                if (isf) ((float*)out)[oi] = val;
                else     ((bf16*)out)[oi]  = __float2bfloat16(val);
            }
        }
    }
}

extern "C" void kernel_launch(void* const* d_in, const int* in_sizes, int n_in,
                              void* d_out, int out_size, void* d_ws, size_t ws_size,
                              hipStream_t stream) {
    const void* x      = d_in[0];
    const void* coords = d_in[1];
    const void* Wqkv   = d_in[2];
    const void* bqkv   = d_in[3];
    const void* Wdist  = d_in[4];
    const void* bdist  = d_in[5];
    const void* Wout   = d_in[6];
    const void* bout   = d_in[7];

    short* qg3   = (short*)d_ws;                       // 16*64*1536 = 1,572,864
    short* kg3   = qg3  + (size_t)1572864;
    short* vg3   = kg3  + (size_t)1572864;             // + 256 overread pad
    short* dist8 = vg3  + (size_t)1573120;             // 2*512*2048*4 = 8,388,608
    short* aob   = dist8 + (size_t)8388608;
    short* WqT   = aob  + (size_t)1572864;
    short* WoT   = WqT  + (size_t)442368;
    float* bqf   = (float*)(WoT + (size_t)147456);     // 16B-aligned
    float* bof   = bqf + QKVN;
    float* wdf   = bof + DM;
    float* bdf   = wdf + NH;

    k_prep<<<dim3(1095), dim3(256), 0, stream>>>(x, coords, Wqkv, Wout, bqkv, bout,
                                                 Wdist, bdist, dist8, WqT, WoT,
                                                 bqf, bof, wdf, bdf);
    k_qkv<<<dim3(64*9), dim3(256), 0, stream>>>(x, WqT, bqf, qg3, kg3, vg3);
    k_attn<<<dim3(512), dim3(256), 0, stream>>>(qg3, kg3, vg3, dist8, wdf, bdf, aob);
    k_out<<<dim3(64*3), dim3(256), 0, stream>>>(aob, WoT, bof, d_out, x);
}

// Round 5
// 146.215 us; speedup vs baseline: 1.1914x; 1.1092x over previous
//
#include <hip/hip_runtime.h>
#include <hip/hip_bf16.h>

#define NB 2
#define SEQ 2048
#define DM 384
#define NH 8
#define HD 48
#define QKVN 1152

typedef __hip_bfloat16 bf16;
typedef __attribute__((ext_vector_type(8))) short short8;
typedef __attribute__((ext_vector_type(4))) float float4v;
typedef __attribute__((ext_vector_type(16))) float f32x16;

static __device__ __forceinline__ float bf2f(bf16 v){ return __bfloat162float(v); }
static __device__ __forceinline__ float ldin(const void* p, size_t i, int isf){
    return isf ? ((const float*)p)[i] : bf2f(((const bf16*)p)[i]);
}
// fp32 -> bf16 bits, RNE
static __device__ __forceinline__ short f2b(float f){
    union { float f; unsigned u; } a; a.f = f;
    unsigned r = a.u + 0x7FFFu + ((a.u >> 16) & 1u);
    return (short)(r >> 16);
}
// packed fp32x2 -> bf16x2 (v_cvt_pk_bf16_f32)
static __device__ __forceinline__ unsigned pk2(float a, float b){
    union { __hip_bfloat162 h; unsigned u; } r;
    r.h = __float22bfloat162_rn(float2{a, b});
    return r.u;
}
static __device__ __forceinline__ float bflo(unsigned u){
    union { unsigned u; float f; } a; a.u = u << 16; return a.f;
}
static __device__ __forceinline__ float bfhi(unsigned u){
    union { unsigned u; float f; } a; a.u = u & 0xFFFF0000u; return a.f;
}
static __device__ __forceinline__ short8 u4pack(unsigned w0, unsigned w1, unsigned w2, unsigned w3){
    union { unsigned u[4]; short8 s; } r; r.u[0]=w0; r.u[1]=w1; r.u[2]=w2; r.u[3]=w3; return r.s;
}
// per-block input dtype probe (0 = bf16, 1 = fp32); wave-uniform
static __device__ __forceinline__ int detect_isf(const void* x){
    const unsigned short* xb = (const unsigned short*)x;
    int l = threadIdx.x & 63;
    union { unsigned u; float f; } a; a.u = ((unsigned)xb[2*l]) << 16;
    float ab = fabsf(a.f);
    int good = (a.f == 0.0f) || (ab > 9.765625e-4f && ab < 1024.0f);
    unsigned long long m = __ballot(good);
    return (__popcll(m) >= 32) ? 0 : 1;
}

// ---------------- K_prep
// sections: [0,512) dist8 | [512,1088) W^T | [1088,1095) misc
// dist8 layout: [b][jg = j>>2 (512)][i(2048)][jj(4)] bf16
// (dist precompute is shared across the 8 heads: 8.4M sqrts once, vs 67M if fused into
//  k_attn — round-2 measured that fusion makes k_attn trans-pipe-bound, 73.7 us.)
__global__ __launch_bounds__(256) void k_prep(const void* __restrict__ x,
    const void* __restrict__ coords,
    const void* __restrict__ Wqkv, const void* __restrict__ Wout,
    const void* __restrict__ bqkv, const void* __restrict__ bout,
    const void* __restrict__ Wdist, const void* __restrict__ bdist,
    short* __restrict__ dist8,
    short* __restrict__ WqT, short* __restrict__ WoT,
    float* __restrict__ bqf, float* __restrict__ bof,
    float* __restrict__ wdf, float* __restrict__ bdf)
{
    const int isf = detect_isf(x);
    const int t = threadIdx.x;
    const int b = blockIdx.x;
    if (b < 512) {
        const int bb = b >> 8;               // batch
        const int jg = (b >> 1) & 127;       // 16-j group
        const int j0 = jg * 16;
        const int ih = (b & 1) * 1024;       // i-half
        __shared__ float cjx[16], cjy[16], cjz[16];
        if (t < 16) {
            int gj = (bb*SEQ + j0 + t)*3;
            cjx[t] = ldin(coords, gj, isf);
            cjy[t] = ldin(coords, gj+1, isf);
            cjz[t] = ldin(coords, gj+2, isf);
        }
        __syncthreads();
        #pragma unroll
        for (int k = 0; k < 4; ++k) {
            int i = ih + k*256 + t;
            int gi = (bb*SEQ + i)*3;
            float px = ldin(coords, gi, isf), py = ldin(coords, gi+1, isf), pz = ldin(coords, gi+2, isf);
            short o[16];
            #pragma unroll
            for (int e = 0; e < 16; ++e) {
                float dx = px - cjx[e], dy = py - cjy[e], dz = pz - cjz[e];
                o[e] = f2b(sqrtf(dx*dx + dy*dy + dz*dz));
            }
            // 4 groups of 4 j each: [b][jg*4+g][i][4]
            short* dst = dist8 + (((size_t)bb*512 + (size_t)jg*4)*SEQ + i)*4;
            *(int2*)(dst)          = *(const int2*)(o);
            *(int2*)(dst + SEQ*4)  = *(const int2*)(o + 4);
            *(int2*)(dst + SEQ*8)  = *(const int2*)(o + 8);
            *(int2*)(dst + SEQ*12) = *(const int2*)(o + 12);
        }
    } else if (b < 1088) {
        int bb, NW; const void* W; short* WT;
        if (b < 944) { bb = b - 512; NW = QKVN; W = Wqkv; WT = WqT; }
        else         { bb = b - 944; NW = DM;   W = Wout; WT = WoT; }
        int ntiles = NW >> 5;
        int kt = bb / ntiles, nt = bb % ntiles;
        int k0 = kt*32, n0 = nt*32;
        __shared__ float Ls[32][33];
        for (int idx = t; idx < 1024; idx += 256) {
            int r = idx >> 5, c = idx & 31;
            Ls[r][c] = ldin(W, (size_t)(k0+r)*NW + n0 + c, isf);
        }
        __syncthreads();
        for (int idx = t; idx < 1024; idx += 256) {
            int r2 = idx >> 5, c2 = idx & 31;
            WT[(size_t)(n0+r2)*DM + k0 + c2] = f2b(Ls[c2][r2]);
        }
    } else {
        int idx = (b - 1088)*256 + t;
        const float log2e = 1.4426950408889634f;
        if (idx < QKVN) bqf[idx] = ldin(bqkv, idx, isf);
        else if (idx < QKVN + DM) bof[idx - QKVN] = ldin(bout, idx - QKVN, isf);
        else if (idx < QKVN + DM + NH) wdf[idx - QKVN - DM] = ldin(Wdist, idx - QKVN - DM, isf)*log2e;
        else if (idx < QKVN + DM + 2*NH) bdf[idx - QKVN - DM - NH] = ldin(bdist, idx - QKVN - DM - NH, isf)*log2e;
    }
}

// ---------------- K1: MFMA GEMM qkv = x @ Wqkv + b; scatter to 32x32x16 frag layouts
// (x read directly, converted to bf16 during As staging — no xb staging pass.)
// qg3/kg3: [bh][t32(64)][dc(3)][hi(2)][tok(32)][e(8)]  elem = X[tok][dc*16 + hi*8 + e]
// vg3:     [bh][jt(64)][jc(2)]{ dt0:[hi][32 d][e8] , dt1:[hi][16 d][e8] } 1536 s/tile.
//          slot (hi,e) holds token j = jc*16 + (e&3) + 8*(e>>2) + 4*hi  (verified 32x32
//          C-row order) so PV's A-operand is the raw sacc register order — no cross-lane.
__global__ __launch_bounds__(256) void k_qkv(const void* __restrict__ x,
    const short* __restrict__ WT, const float* __restrict__ bias,
    short* __restrict__ qg3, short* __restrict__ kg3, short* __restrict__ vg3)
{
    __shared__ __align__(16) short As[64*72];
    __shared__ __align__(16) short Bs[128*72];   // reused as epilogue buffer
    const int isf = detect_isf(x);
    const int t = threadIdx.x;
    const int w = t >> 6, lane = t & 63, L = lane & 15, quad = lane >> 4;
    const int mt = blockIdx.x / 9, nt = blockIdx.x % 9;
    const int row0 = mt*64, col0 = nt*128;
    const int wm = w & 1, wn = w >> 1;
    float4v acc[2][4] = {};
    for (int k0 = 0; k0 < DM; k0 += 64) {
        __syncthreads();
        for (int c = t; c < 512; c += 256) {
            int row = c >> 3, k8 = c & 7;
            size_t src = (size_t)(row0+row)*DM + k0 + k8*8;
            if (isf) {
                const float* xf = (const float*)x + src;
                short o[8];
                #pragma unroll
                for (int e = 0; e < 8; ++e) o[e] = f2b(xf[e]);
                *(int4*)(&As[row*72 + k8*8]) = *(const int4*)o;
            } else {
                *(int4*)(&As[row*72 + k8*8]) = *(const int4*)((const short*)x + src);
            }
        }
        for (int c = t; c < 1024; c += 256) {
            int row = c >> 3, k8 = c & 7;
            *(int4*)(&Bs[row*72 + k8*8]) = *(const int4*)(WT + (size_t)(col0+row)*DM + k0 + k8*8);
        }
        __syncthreads();
        #pragma unroll
        for (int kc = 0; kc < 2; ++kc) {
            short8 a0 = *(const short8*)(&As[(32*wm + L)*72 + kc*32 + quad*8]);
            short8 a1 = *(const short8*)(&As[(32*wm + 16 + L)*72 + kc*32 + quad*8]);
            #pragma unroll
            for (int ni = 0; ni < 4; ++ni) {
                short8 bf = *(const short8*)(&Bs[(64*wn + 16*ni + L)*72 + kc*32 + quad*8]);
                acc[0][ni] = __builtin_amdgcn_mfma_f32_16x16x32_bf16(a0, bf, acc[0][ni], 0, 0, 0);
                acc[1][ni] = __builtin_amdgcn_mfma_f32_16x16x32_bf16(a1, bf, acc[1][ni], 0, 0, 0);
            }
        }
    }
    const int which = col0 / DM;     // uniform per block (0=q,1=k,2=v)
    const int cbase = col0 % DM;
    short* Ep = Bs;
    __syncthreads();
    if (which < 2) {
        // row-major Ep[64 tokens][136]
        #pragma unroll
        for (int mi = 0; mi < 2; ++mi)
            #pragma unroll
            for (int ni = 0; ni < 4; ++ni) {
                int col_l = 64*wn + 16*ni + L;
                float bv = bias[col0 + col_l];
                #pragma unroll
                for (int r = 0; r < 4; ++r) {
                    int row_l = 32*wm + 16*mi + quad*4 + r;
                    Ep[row_l*136 + col_l] = f2b(acc[mi][ni][r] + bv);
                }
            }
        __syncthreads();
        short* dst = which ? kg3 : qg3;
        for (int c = t; c < 1024; c += 256) {
            int row_l = c >> 4, col_l = (c & 15)*8;   // 8 consecutive d, one token
            int row_g = row0 + row_l;
            int bi = row_g >> 11, nn = row_g & (SEQ-1);
            int c2 = cbase + col_l;
            int hh = c2/HD, dh = c2%HD;
            int bh = bi*NH + hh;
            int dc = dh >> 4, hi = (dh >> 3) & 1;
            size_t dstoff = ((size_t)bh*64 + (nn>>5))*1536 + (size_t)((dc*2 + hi)*256 + (nn&31)*8);
            *(int4*)(dst + dstoff) = *(const int4*)(&Ep[row_l*136 + col_l]);
        }
    } else {
        // col-major Ep[128 cols][72 tokens]
        #pragma unroll
        for (int mi = 0; mi < 2; ++mi)
            #pragma unroll
            for (int ni = 0; ni < 4; ++ni) {
                int col_l = 64*wn + 16*ni + L;
                float bv = bias[col0 + col_l];
                #pragma unroll
                for (int r = 0; r < 4; ++r) {
                    int row_l = 32*wm + 16*mi + quad*4 + r;
                    Ep[col_l*72 + row_l] = f2b(acc[mi][ni][r] + bv);
                }
            }
        __syncthreads();
        for (int c = t; c < 1024; c += 256) {
            int col_l = c >> 3, row8 = (c & 7)*8;     // 8 consecutive tokens, one d
            int row_g = row0 + row8;
            int bi = row_g >> 11, nn = row_g & (SEQ-1);
            int c2 = cbase + col_l;
            int hh = c2/HD, dh = c2%HD;
            int bh = bi*NH + hh;
            int jt = nn >> 5, jc = (nn >> 4) & 1;
            int ehalf = ((nn >> 3) & 1)*4;            // e>>2 half of the slot
            int dt = dh >> 5, dp = dh & 31;           // d-tile 0: 32 cols, d-tile 1: 16 cols
            int hstride = dt ? 128 : 256;
            size_t base = ((size_t)bh*64 + jt)*1536 + (size_t)(jc*768 + dt*512 + dp*8 + ehalf);
            *(int2*)(vg3 + base)           = *(const int2*)(&Ep[col_l*72 + row8]);
            *(int2*)(vg3 + base + hstride) = *(const int2*)(&Ep[col_l*72 + row8 + 4]);
        }
    }
}

// ---------------- K2: flash attention on 32x32x16 MFMA, 32 i per block, grid 1024
// Round-3 post-mortem: 64-i/512-block version was latency-bound (Occupancy 18%, nothing
// saturated, dur 46 us). 1024 blocks @ 4/CU = 16 waves/CU is the binding resource here.
// 4 waves split the j-range (wave w: tiles 4s+w). QK^T: 3 pad-free K=16 MFMA; sacc:
// i = lane&31, slot r -> j = jb + (r&3) + 8*(r>>2) + 4*hi (m74/m101). PV: pa in raw sacc
// register order (V slot-permuted at prep). 7 MFMA/iter.
// Swizzle: XCD x hosts all 8 heads of one (batch, 16-it band): dist8 slice (2 MB) shared
// 8x across heads through L2/L3; dist8 read ~once from HBM (harness fill evicts L3).
__global__ __launch_bounds__(256, 4) void k_attn(
    const short* __restrict__ qg3, const short* __restrict__ kg3, const short* __restrict__ vg3,
    const short* __restrict__ dist8, const float* __restrict__ wdf,
    const float* __restrict__ bdf, short* __restrict__ aob)
{
    __shared__ float Ored[2][32*48];
    __shared__ float Lred[2][32];
    const int t = threadIdx.x;
    const int w = t >> 6, lane = t & 63;
    const int li = lane & 31, hi = lane >> 5;
    const int xcd  = blockIdx.x & 7;
    const int slot = blockIdx.x >> 3;        // 0..127
    const int bi   = xcd >> 2;               // batch
    const int band = xcd & 3;                // 16-it band
    const int hh   = slot & 7;
    const int it   = band*16 + (slot >> 3);  // 0..63
    const int bh   = bi*NH + hh;
    const int i0 = it*32;
    const float scale2 = 0.14433756729740643f * 1.4426950408889634f;
    const float wd = wdf[hh], bd = bdf[hh];     // pre-scaled by log2e

    const short* qB = qg3 + ((size_t)bh*64 + it)*1536 + hi*256 + li*8;
    const short8 qf0 = *(const short8*)(qB);
    const short8 qf1 = *(const short8*)(qB + 512);
    const short8 qf2 = *(const short8*)(qB + 1024);

    f32x16 accO0 = {}, accO1 = {};
    float rsum = 0.0f;

    const short* kBp = kg3 + ((size_t)bh*64 + w)*1536 + hi*256 + li*8;
    const short* vBp = vg3 + ((size_t)bh*64 + w)*1536 + li*8;
    const short* dBp = dist8 + (((size_t)bi*512 + (size_t)w*8 + hi)*SEQ + i0 + li)*4;

    for (int s = 0; s < 16; ++s) {
        short8 kf0 = *(const short8*)(kBp);
        short8 kf1 = *(const short8*)(kBp + 512);
        short8 kf2 = *(const short8*)(kBp + 1024);
        int2 du0 = *(const int2*)(dBp);
        int2 du1 = *(const int2*)(dBp + SEQ*8);
        int2 du2 = *(const int2*)(dBp + SEQ*16);
        int2 du3 = *(const int2*)(dBp + SEQ*24);
        f32x16 sacc = {};
        sacc = __builtin_amdgcn_mfma_f32_32x32x16_bf16(kf0, qf0, sacc, 0, 0, 0);
        sacc = __builtin_amdgcn_mfma_f32_32x32x16_bf16(kf1, qf1, sacc, 0, 0, 0);
        sacc = __builtin_amdgcn_mfma_f32_32x32x16_bf16(kf2, qf2, sacc, 0, 0, 0);
        float p[16];
        #pragma unroll
        for (int rq = 0; rq < 4; ++rq) {
            int2 du = rq == 0 ? du0 : rq == 1 ? du1 : rq == 2 ? du2 : du3;
            float d0 = bflo((unsigned)du.x), d1 = bfhi((unsigned)du.x);
            float d2 = bflo((unsigned)du.y), d3 = bfhi((unsigned)du.y);
            p[4*rq+0] = __builtin_amdgcn_exp2f(fmaf(sacc[4*rq+0], scale2, fmaf(d0, wd, bd)));
            p[4*rq+1] = __builtin_amdgcn_exp2f(fmaf(sacc[4*rq+1], scale2, fmaf(d1, wd, bd)));
            p[4*rq+2] = __builtin_amdgcn_exp2f(fmaf(sacc[4*rq+2], scale2, fmaf(d2, wd, bd)));
            p[4*rq+3] = __builtin_amdgcn_exp2f(fmaf(sacc[4*rq+3], scale2, fmaf(d3, wd, bd)));
            rsum += (p[4*rq+0] + p[4*rq+1]) + (p[4*rq+2] + p[4*rq+3]);
        }
        short8 pa0 = u4pack(pk2(p[0],p[1]),  pk2(p[2],p[3]),  pk2(p[4],p[5]),   pk2(p[6],p[7]));
        short8 pa1 = u4pack(pk2(p[8],p[9]),  pk2(p[10],p[11]),pk2(p[12],p[13]), pk2(p[14],p[15]));
        short8 v00 = *(const short8*)(vBp + hi*256);            // jc0, d 0..31
        short8 v10 = *(const short8*)(vBp + 768 + hi*256);      // jc1, d 0..31
        accO0 = __builtin_amdgcn_mfma_f32_32x32x16_bf16(pa0, v00, accO0, 0, 0, 0);
        accO0 = __builtin_amdgcn_mfma_f32_32x32x16_bf16(pa1, v10, accO0, 0, 0, 0);
        short8 v01 = *(const short8*)(vBp + 512 + hi*128);      // jc0, d 32..47 (cols>=16 junk)
        short8 v11 = *(const short8*)(vBp + 1280 + hi*128);     // jc1, d 32..47
        accO1 = __builtin_amdgcn_mfma_f32_32x32x16_bf16(pa0, v01, accO1, 0, 0, 0);
        accO1 = __builtin_amdgcn_mfma_f32_32x32x16_bf16(pa1, v11, accO1, 0, 0, 0);
        kBp += 4*1536; vBp += 4*1536; dBp += (size_t)SEQ*128;
    }
    rsum += __shfl_xor(rsum, 32);   // partner half-lane holds the other 16 j per tile

    // cross-wave tree reduction
    if (w >= 2) {
        float* Od = Ored[w-2];
        #pragma unroll
        for (int r = 0; r < 16; ++r) {
            int ii = (r & 3) + 8*(r >> 2) + 4*hi;
            Od[ii*48 + li] = accO0[r];
            if (li < 16) Od[ii*48 + 32 + li] = accO1[r];
        }
        if (lane < 32) Lred[w-2][lane] = rsum;
    }
    __syncthreads();
    if (w < 2) {
        const float* Od = Ored[w];
        #pragma unroll
        for (int r = 0; r < 16; ++r) {
            int ii = (r & 3) + 8*(r >> 2) + 4*hi;
            accO0[r] += Od[ii*48 + li];
            accO1[r] += Od[ii*48 + 32 + (li & 15)];
        }
        rsum += Lred[w][li];
    }
    __syncthreads();
    if (w == 1) {
        float* Od = Ored[0];
        #pragma unroll
        for (int r = 0; r < 16; ++r) {
            int ii = (r & 3) + 8*(r >> 2) + 4*hi;
            Od[ii*48 + li] = accO0[r];
            if (li < 16) Od[ii*48 + 32 + li] = accO1[r];
        }
        if (lane < 32) Lred[0][lane] = rsum;
    }
    __syncthreads();
    if (w == 0) {
        float* Od = Ored[0];
        #pragma unroll
        for (int r = 0; r < 16; ++r) {
            int ii = (r & 3) + 8*(r >> 2) + 4*hi;
            Od[ii*48 + li] += accO0[r];
            if (li < 16) Od[ii*48 + 32 + li] += accO1[r];
        }
        if (lane < 32) Lred[0][lane] += rsum;
    }
    __syncthreads();
    // all waves: normalize + coalesced int4 store of the 32x48 tile
    for (int c = t; c < 192; c += 256) {
        int r = c / 6, d8 = (c % 6)*8;
        float inv = 1.0f / Lred[0][r];
        const float* src = &Ored[0][r*48 + d8];
        short o[8];
        #pragma unroll
        for (int e = 0; e < 8; ++e) o[e] = f2b(src[e]*inv);
        *(int4*)(aob + ((size_t)(bi*SEQ) + i0 + r)*DM + hh*HD + d8) = *(const int4*)o;
    }
}

// ---------------- K3: MFMA GEMM out = aob @ Wout + b_out
__global__ __launch_bounds__(256) void k_out(const short* __restrict__ aob,
    const short* __restrict__ WT, const float* __restrict__ bias,
    void* __restrict__ out, const void* __restrict__ x)
{
    __shared__ __align__(16) short As[64*72];
    __shared__ __align__(16) short Bs[128*72];
    const int isf = detect_isf(x);
    const int t = threadIdx.x;
    const int w = t >> 6, lane = t & 63, L = lane & 15, quad = lane >> 4;
    const int mt = blockIdx.x / 3, nt = blockIdx.x % 3;
    const int row0 = mt*64, col0 = nt*128;
    const int wm = w & 1, wn = w >> 1;
    float4v acc[2][4] = {};
    for (int k0 = 0; k0 < DM; k0 += 64) {
        __syncthreads();
        for (int c = t; c < 512; c += 256) {
            int row = c >> 3, k8 = c & 7;
            *(int4*)(&As[row*72 + k8*8]) = *(const int4*)(aob + (size_t)(row0+row)*DM + k0 + k8*8);
        }
        for (int c = t; c < 1024; c += 256) {
            int row = c >> 3, k8 = c & 7;
            *(int4*)(&Bs[row*72 + k8*8]) = *(const int4*)(WT + (size_t)(col0+row)*DM + k0 + k8*8);
        }
        __syncthreads();
        #pragma unroll
        for (int kc = 0; kc < 2; ++kc) {
            short8 a0 = *(const short8*)(&As[(32*wm + L)*72 + kc*32 + quad*8]);
            short8 a1 = *(const short8*)(&As[(32*wm + 16 + L)*72 + kc*32 + quad*8]);
            #pragma unroll
            for (int ni = 0; ni < 4; ++ni) {
                short8 bf = *(const short8*)(&Bs[(64*wn + 16*ni + L)*72 + kc*32 + quad*8]);
                acc[0][ni] = __builtin_amdgcn_mfma_f32_16x16x32_bf16(a0, bf, acc[0][ni], 0, 0, 0);
                acc[1][ni] = __builtin_amdgcn_mfma_f32_16x16x32_bf16(a1, bf, acc[1][ni], 0, 0, 0);
            }
        }
    }
    #pragma unroll
    for (int mi = 0; mi < 2; ++mi) {
        #pragma unroll
        for (int ni = 0; ni < 4; ++ni) {
            int col_g = col0 + 64*wn + 16*ni + L;
            float bv = bias[col_g];
            #pragma unroll
            for (int r = 0; r < 4; ++r) {
                int row_g = row0 + 32*wm + 16*mi + quad*4 + r;
                size_t oi = (size_t)row_g*DM + col_g;
                float val = acc[mi][ni][r] + bv;
                if (isf) ((float*)out)[oi] = val;
                else     ((bf16*)out)[oi]  = __float2bfloat16(val);
            }
        }
    }
}

extern "C" void kernel_launch(void* const* d_in, const int* in_sizes, int n_in,
                              void* d_out, int out_size, void* d_ws, size_t ws_size,
                              hipStream_t stream) {
    const void* x      = d_in[0];
    const void* coords = d_in[1];
    const void* Wqkv   = d_in[2];
    const void* bqkv   = d_in[3];
    const void* Wdist  = d_in[4];
    const void* bdist  = d_in[5];
    const void* Wout   = d_in[6];
    const void* bout   = d_in[7];

    short* qg3   = (short*)d_ws;                       // 16*64*1536 = 1,572,864
    short* kg3   = qg3  + (size_t)1572864;
    short* vg3   = kg3  + (size_t)1572864;             // + 256 overread pad
    short* dist8 = vg3  + (size_t)1573120;             // 2*512*2048*4 = 8,388,608
    short* aob   = dist8 + (size_t)8388608;
    short* WqT   = aob  + (size_t)1572864;
    short* WoT   = WqT  + (size_t)442368;
    float* bqf   = (float*)(WoT + (size_t)147456);     // 16B-aligned
    float* bof   = bqf + QKVN;
    float* wdf   = bof + DM;
    float* bdf   = wdf + NH;

    k_prep<<<dim3(1095), dim3(256), 0, stream>>>(x, coords, Wqkv, Wout, bqkv, bout,
                                                 Wdist, bdist, dist8, WqT, WoT,
                                                 bqf, bof, wdf, bdf);
    k_qkv<<<dim3(64*9), dim3(256), 0, stream>>>(x, WqT, bqf, qg3, kg3, vg3);
    k_attn<<<dim3(1024), dim3(256), 0, stream>>>(qg3, kg3, vg3, dist8, wdf, bdf, aob);
    k_out<<<dim3(64*3), dim3(256), 0, stream>>>(aob, WoT, bof, d_out, x);
}

// Round 6
// 143.837 us; speedup vs baseline: 1.2111x; 1.0165x over previous
//
#include <hip/hip_runtime.h>
#include <hip/hip_bf16.h>

#define NB 2
#define SEQ 2048
#define DM 384
#define NH 8
#define HD 48
#define QKVN 1152

typedef __hip_bfloat16 bf16;
typedef __attribute__((ext_vector_type(8))) short short8;
typedef __attribute__((ext_vector_type(4))) float float4v;
typedef __attribute__((ext_vector_type(16))) float f32x16;

static __device__ __forceinline__ float bf2f(bf16 v){ return __bfloat162float(v); }
static __device__ __forceinline__ float ldin(const void* p, size_t i, int isf){
    return isf ? ((const float*)p)[i] : bf2f(((const bf16*)p)[i]);
}
// fp32 -> bf16 bits, RNE
static __device__ __forceinline__ short f2b(float f){
    union { float f; unsigned u; } a; a.f = f;
    unsigned r = a.u + 0x7FFFu + ((a.u >> 16) & 1u);
    return (short)(r >> 16);
}
// packed fp32x2 -> bf16x2 (v_cvt_pk_bf16_f32)
static __device__ __forceinline__ unsigned pk2(float a, float b){
    union { __hip_bfloat162 h; unsigned u; } r;
    r.h = __float22bfloat162_rn(float2{a, b});
    return r.u;
}
static __device__ __forceinline__ float bflo(unsigned u){
    union { unsigned u; float f; } a; a.u = u << 16; return a.f;
}
static __device__ __forceinline__ float bfhi(unsigned u){
    union { unsigned u; float f; } a; a.u = u & 0xFFFF0000u; return a.f;
}
static __device__ __forceinline__ short8 u4pack(unsigned w0, unsigned w1, unsigned w2, unsigned w3){
    union { unsigned u[4]; short8 s; } r; r.u[0]=w0; r.u[1]=w1; r.u[2]=w2; r.u[3]=w3; return r.s;
}
// per-block input dtype probe (0 = bf16, 1 = fp32); wave-uniform
static __device__ __forceinline__ int detect_isf(const void* x){
    const unsigned short* xb = (const unsigned short*)x;
    int l = threadIdx.x & 63;
    union { unsigned u; float f; } a; a.u = ((unsigned)xb[2*l]) << 16;
    float ab = fabsf(a.f);
    int good = (a.f == 0.0f) || (ab > 9.765625e-4f && ab < 1024.0f);
    unsigned long long m = __ballot(good);
    return (__popcll(m) >= 32) ? 0 : 1;
}

// ---------------- K1: W^T transposes + bias misc (tiny, runs first)
// [0,432) WqT | [432,576) WoT | [576,583) misc
__global__ __launch_bounds__(256) void k_wt(const void* __restrict__ x,
    const void* __restrict__ Wqkv, const void* __restrict__ Wout,
    const void* __restrict__ bqkv, const void* __restrict__ bout,
    const void* __restrict__ Wdist, const void* __restrict__ bdist,
    short* __restrict__ WqT, short* __restrict__ WoT,
    float* __restrict__ bqf, float* __restrict__ bof,
    float* __restrict__ wdf, float* __restrict__ bdf)
{
    const int isf = detect_isf(x);
    const int t = threadIdx.x;
    const int b = blockIdx.x;
    if (b < 576) {
        int bb, NW; const void* W; short* WT;
        if (b < 432) { bb = b;       NW = QKVN; W = Wqkv; WT = WqT; }
        else         { bb = b - 432; NW = DM;   W = Wout; WT = WoT; }
        int ntiles = NW >> 5;
        int kt = bb / ntiles, nt = bb % ntiles;
        int k0 = kt*32, n0 = nt*32;
        __shared__ float Ls[32][33];
        for (int idx = t; idx < 1024; idx += 256) {
            int r = idx >> 5, c = idx & 31;
            Ls[r][c] = ldin(W, (size_t)(k0+r)*NW + n0 + c, isf);
        }
        __syncthreads();
        for (int idx = t; idx < 1024; idx += 256) {
            int r2 = idx >> 5, c2 = idx & 31;
            WT[(size_t)(n0+r2)*DM + k0 + c2] = f2b(Ls[c2][r2]);
        }
    } else {
        int idx = (b - 576)*256 + t;
        const float log2e = 1.4426950408889634f;
        if (idx < QKVN) bqf[idx] = ldin(bqkv, idx, isf);
        else if (idx < QKVN + DM) bof[idx - QKVN] = ldin(bout, idx - QKVN, isf);
        else if (idx < QKVN + DM + NH) wdf[idx - QKVN - DM] = ldin(Wdist, idx - QKVN - DM, isf)*log2e;
        else if (idx < QKVN + DM + 2*NH) bdf[idx - QKVN - DM - NH] = ldin(bdist, idx - QKVN - DM - NH, isf)*log2e;
    }
}

// ---------------- K2: fused {qkv GEMM | dist8} — independent sections co-scheduled.
// Round-5 post-mortem: dist section cost ~15 us serial in k_prep (round2-vs-3 delta);
// qkv alone is 576 blocks = 2.25/CU, latency-bound -> dist blocks fill the idle CUs.
// qkv section: GEMM qkv = x @ Wqkv + b (x read directly, converted during As staging);
//   scatter to 32x32x16 frag layouts:
// qg3/kg3: [bh][t32(64)][dc(3)][hi(2)][tok(32)][e(8)]  elem = X[tok][dc*16 + hi*8 + e]
// vg3:     [bh][jt(64)][jc(2)]{ dt0:[hi][32 d][e8] , dt1:[hi][16 d][e8] } 1536 s/tile.
//          slot (hi,e) holds token j = jc*16 + (e&3) + 8*(e>>2) + 4*hi (verified 32x32
//          C-row order) so PV's A-operand is the raw sacc register order — no cross-lane.
// dist section: dist8[b][jg = j>>2 (512)][i(2048)][jj(4)] bf16. Precomputed once, shared
//   across 8 heads (round-2: fusing into attn makes it trans-pipe-bound, 73.7 us).
__global__ __launch_bounds__(256) void k_qkv_dist(const void* __restrict__ x,
    const void* __restrict__ coords,
    const short* __restrict__ WT, const float* __restrict__ bias,
    short* __restrict__ qg3, short* __restrict__ kg3, short* __restrict__ vg3,
    short* __restrict__ dist8)
{
    __shared__ __align__(16) short As[64*72];
    __shared__ __align__(16) short Bs[128*72];   // reused as epilogue buffer
    __shared__ float cjx[16], cjy[16], cjz[16];
    const int isf = detect_isf(x);
    const int t = threadIdx.x;
    if (blockIdx.x >= 576) {
        // ---- dist section
        const int b = blockIdx.x - 576;      // 0..511
        const int bb = b >> 8;               // batch
        const int jg = (b >> 1) & 127;       // 16-j group
        const int j0 = jg * 16;
        const int ih = (b & 1) * 1024;       // i-half
        if (t < 16) {
            int gj = (bb*SEQ + j0 + t)*3;
            cjx[t] = ldin(coords, gj, isf);
            cjy[t] = ldin(coords, gj+1, isf);
            cjz[t] = ldin(coords, gj+2, isf);
        }
        __syncthreads();
        #pragma unroll
        for (int k = 0; k < 4; ++k) {
            int i = ih + k*256 + t;
            int gi = (bb*SEQ + i)*3;
            float px = ldin(coords, gi, isf), py = ldin(coords, gi+1, isf), pz = ldin(coords, gi+2, isf);
            short o[16];
            #pragma unroll
            for (int e = 0; e < 16; ++e) {
                float dx = px - cjx[e], dy = py - cjy[e], dz = pz - cjz[e];
                o[e] = f2b(sqrtf(dx*dx + dy*dy + dz*dz));
            }
            // 4 groups of 4 j each: [b][jg*4+g][i][4]
            short* dst = dist8 + (((size_t)bb*512 + (size_t)jg*4)*SEQ + i)*4;
            *(int2*)(dst)          = *(const int2*)(o);
            *(int2*)(dst + SEQ*4)  = *(const int2*)(o + 4);
            *(int2*)(dst + SEQ*8)  = *(const int2*)(o + 8);
            *(int2*)(dst + SEQ*12) = *(const int2*)(o + 12);
        }
        return;
    }
    // ---- qkv GEMM section
    const int w = t >> 6, lane = t & 63, L = lane & 15, quad = lane >> 4;
    const int mt = blockIdx.x / 9, nt = blockIdx.x % 9;
    const int row0 = mt*64, col0 = nt*128;
    const int wm = w & 1, wn = w >> 1;
    float4v acc[2][4] = {};
    for (int k0 = 0; k0 < DM; k0 += 64) {
        __syncthreads();
        for (int c = t; c < 512; c += 256) {
            int row = c >> 3, k8 = c & 7;
            size_t src = (size_t)(row0+row)*DM + k0 + k8*8;
            if (isf) {
                const float* xf = (const float*)x + src;
                short o[8];
                #pragma unroll
                for (int e = 0; e < 8; ++e) o[e] = f2b(xf[e]);
                *(int4*)(&As[row*72 + k8*8]) = *(const int4*)o;
            } else {
                *(int4*)(&As[row*72 + k8*8]) = *(const int4*)((const short*)x + src);
            }
        }
        for (int c = t; c < 1024; c += 256) {
            int row = c >> 3, k8 = c & 7;
            *(int4*)(&Bs[row*72 + k8*8]) = *(const int4*)(WT + (size_t)(col0+row)*DM + k0 + k8*8);
        }
        __syncthreads();
        #pragma unroll
        for (int kc = 0; kc < 2; ++kc) {
            short8 a0 = *(const short8*)(&As[(32*wm + L)*72 + kc*32 + quad*8]);
            short8 a1 = *(const short8*)(&As[(32*wm + 16 + L)*72 + kc*32 + quad*8]);
            #pragma unroll
            for (int ni = 0; ni < 4; ++ni) {
                short8 bf = *(const short8*)(&Bs[(64*wn + 16*ni + L)*72 + kc*32 + quad*8]);
                acc[0][ni] = __builtin_amdgcn_mfma_f32_16x16x32_bf16(a0, bf, acc[0][ni], 0, 0, 0);
                acc[1][ni] = __builtin_amdgcn_mfma_f32_16x16x32_bf16(a1, bf, acc[1][ni], 0, 0, 0);
            }
        }
    }
    const int which = col0 / DM;     // uniform per block (0=q,1=k,2=v)
    const int cbase = col0 % DM;
    short* Ep = Bs;
    __syncthreads();
    if (which < 2) {
        // row-major Ep[64 tokens][136]
        #pragma unroll
        for (int mi = 0; mi < 2; ++mi)
            #pragma unroll
            for (int ni = 0; ni < 4; ++ni) {
                int col_l = 64*wn + 16*ni + L;
                float bv = bias[col0 + col_l];
                #pragma unroll
                for (int r = 0; r < 4; ++r) {
                    int row_l = 32*wm + 16*mi + quad*4 + r;
                    Ep[row_l*136 + col_l] = f2b(acc[mi][ni][r] + bv);
                }
            }
        __syncthreads();
        short* dst = which ? kg3 : qg3;
        for (int c = t; c < 1024; c += 256) {
            int row_l = c >> 4, col_l = (c & 15)*8;   // 8 consecutive d, one token
            int row_g = row0 + row_l;
            int bi = row_g >> 11, nn = row_g & (SEQ-1);
            int c2 = cbase + col_l;
            int hh = c2/HD, dh = c2%HD;
            int bh = bi*NH + hh;
            int dc = dh >> 4, hi = (dh >> 3) & 1;
            size_t dstoff = ((size_t)bh*64 + (nn>>5))*1536 + (size_t)((dc*2 + hi)*256 + (nn&31)*8);
            *(int4*)(dst + dstoff) = *(const int4*)(&Ep[row_l*136 + col_l]);
        }
    } else {
        // col-major Ep[128 cols][72 tokens]
        #pragma unroll
        for (int mi = 0; mi < 2; ++mi)
            #pragma unroll
            for (int ni = 0; ni < 4; ++ni) {
                int col_l = 64*wn + 16*ni + L;
                float bv = bias[col0 + col_l];
                #pragma unroll
                for (int r = 0; r < 4; ++r) {
                    int row_l = 32*wm + 16*mi + quad*4 + r;
                    Ep[col_l*72 + row_l] = f2b(acc[mi][ni][r] + bv);
                }
            }
        __syncthreads();
        for (int c = t; c < 1024; c += 256) {
            int col_l = c >> 3, row8 = (c & 7)*8;     // 8 consecutive tokens, one d
            int row_g = row0 + row8;
            int bi = row_g >> 11, nn = row_g & (SEQ-1);
            int c2 = cbase + col_l;
            int hh = c2/HD, dh = c2%HD;
            int bh = bi*NH + hh;
            int jt = nn >> 5, jc = (nn >> 4) & 1;
            int ehalf = ((nn >> 3) & 1)*4;            // e>>2 half of the slot
            int dt = dh >> 5, dp = dh & 31;           // d-tile 0: 32 cols, d-tile 1: 16 cols
            int hstride = dt ? 128 : 256;
            size_t base = ((size_t)bh*64 + jt)*1536 + (size_t)(jc*768 + dt*512 + dp*8 + ehalf);
            *(int2*)(vg3 + base)           = *(const int2*)(&Ep[col_l*72 + row8]);
            *(int2*)(vg3 + base + hstride) = *(const int2*)(&Ep[col_l*72 + row8 + 4]);
        }
    }
}

// ---------------- K3: flash attention on 32x32x16 MFMA, 32 i per block, grid 1024
// 4/CU = 16 waves/CU (round-3: 512-block version was latency-bound at 2/CU).
// 4 waves split the j-range (wave w: tiles 4s+w). QK^T: 3 pad-free K=16 MFMA; sacc:
// i = lane&31, slot r -> j = jb + (r&3) + 8*(r>>2) + 4*hi (m74/m101). PV: pa in raw sacc
// register order (V slot-permuted at prep). 7 MFMA/iter. setprio around MFMA clusters:
// waves here are barrier-free/independent — the regime where T5 measured +4-7% (m191).
// Swizzle: XCD x hosts all 8 heads of one (batch, 16-it band): dist8 slice (2 MB) shared
// 8x across heads through L2/L3.
__global__ __launch_bounds__(256, 4) void k_attn(
    const short* __restrict__ qg3, const short* __restrict__ kg3, const short* __restrict__ vg3,
    const short* __restrict__ dist8, const float* __restrict__ wdf,
    const float* __restrict__ bdf, short* __restrict__ aob)
{
    __shared__ float Ored[2][32*48];
    __shared__ float Lred[2][32];
    const int t = threadIdx.x;
    const int w = t >> 6, lane = t & 63;
    const int li = lane & 31, hi = lane >> 5;
    const int xcd  = blockIdx.x & 7;
    const int slot = blockIdx.x >> 3;        // 0..127
    const int bi   = xcd >> 2;               // batch
    const int band = xcd & 3;                // 16-it band
    const int hh   = slot & 7;
    const int it   = band*16 + (slot >> 3);  // 0..63
    const int bh   = bi*NH + hh;
    const int i0 = it*32;
    const float scale2 = 0.14433756729740643f * 1.4426950408889634f;
    const float wd = wdf[hh], bd = bdf[hh];     // pre-scaled by log2e

    const short* qB = qg3 + ((size_t)bh*64 + it)*1536 + hi*256 + li*8;
    const short8 qf0 = *(const short8*)(qB);
    const short8 qf1 = *(const short8*)(qB + 512);
    const short8 qf2 = *(const short8*)(qB + 1024);

    f32x16 accO0 = {}, accO1 = {};
    float rsum = 0.0f;

    const short* kBp = kg3 + ((size_t)bh*64 + w)*1536 + hi*256 + li*8;
    const short* vBp = vg3 + ((size_t)bh*64 + w)*1536 + li*8;
    const short* dBp = dist8 + (((size_t)bi*512 + (size_t)w*8 + hi)*SEQ + i0 + li)*4;

    for (int s = 0; s < 16; ++s) {
        short8 kf0 = *(const short8*)(kBp);
        short8 kf1 = *(const short8*)(kBp + 512);
        short8 kf2 = *(const short8*)(kBp + 1024);
        int2 du0 = *(const int2*)(dBp);
        int2 du1 = *(const int2*)(dBp + SEQ*8);
        int2 du2 = *(const int2*)(dBp + SEQ*16);
        int2 du3 = *(const int2*)(dBp + SEQ*24);
        f32x16 sacc = {};
        __builtin_amdgcn_s_setprio(1);
        sacc = __builtin_amdgcn_mfma_f32_32x32x16_bf16(kf0, qf0, sacc, 0, 0, 0);
        sacc = __builtin_amdgcn_mfma_f32_32x32x16_bf16(kf1, qf1, sacc, 0, 0, 0);
        sacc = __builtin_amdgcn_mfma_f32_32x32x16_bf16(kf2, qf2, sacc, 0, 0, 0);
        __builtin_amdgcn_s_setprio(0);
        float p[16];
        #pragma unroll
        for (int rq = 0; rq < 4; ++rq) {
            int2 du = rq == 0 ? du0 : rq == 1 ? du1 : rq == 2 ? du2 : du3;
            float d0 = bflo((unsigned)du.x), d1 = bfhi((unsigned)du.x);
            float d2 = bflo((unsigned)du.y), d3 = bfhi((unsigned)du.y);
            p[4*rq+0] = __builtin_amdgcn_exp2f(fmaf(sacc[4*rq+0], scale2, fmaf(d0, wd, bd)));
            p[4*rq+1] = __builtin_amdgcn_exp2f(fmaf(sacc[4*rq+1], scale2, fmaf(d1, wd, bd)));
            p[4*rq+2] = __builtin_amdgcn_exp2f(fmaf(sacc[4*rq+2], scale2, fmaf(d2, wd, bd)));
            p[4*rq+3] = __builtin_amdgcn_exp2f(fmaf(sacc[4*rq+3], scale2, fmaf(d3, wd, bd)));
            rsum += (p[4*rq+0] + p[4*rq+1]) + (p[4*rq+2] + p[4*rq+3]);
        }
        short8 pa0 = u4pack(pk2(p[0],p[1]),  pk2(p[2],p[3]),  pk2(p[4],p[5]),   pk2(p[6],p[7]));
        short8 pa1 = u4pack(pk2(p[8],p[9]),  pk2(p[10],p[11]),pk2(p[12],p[13]), pk2(p[14],p[15]));
        short8 v00 = *(const short8*)(vBp + hi*256);            // jc0, d 0..31
        short8 v10 = *(const short8*)(vBp + 768 + hi*256);      // jc1, d 0..31
        short8 v01 = *(const short8*)(vBp + 512 + hi*128);      // jc0, d 32..47 (cols>=16 junk)
        short8 v11 = *(const short8*)(vBp + 1280 + hi*128);     // jc1, d 32..47
        __builtin_amdgcn_s_setprio(1);
        accO0 = __builtin_amdgcn_mfma_f32_32x32x16_bf16(pa0, v00, accO0, 0, 0, 0);
        accO0 = __builtin_amdgcn_mfma_f32_32x32x16_bf16(pa1, v10, accO0, 0, 0, 0);
        accO1 = __builtin_amdgcn_mfma_f32_32x32x16_bf16(pa0, v01, accO1, 0, 0, 0);
        accO1 = __builtin_amdgcn_mfma_f32_32x32x16_bf16(pa1, v11, accO1, 0, 0, 0);
        __builtin_amdgcn_s_setprio(0);
        kBp += 4*1536; vBp += 4*1536; dBp += (size_t)SEQ*128;
    }
    rsum += __shfl_xor(rsum, 32);   // partner half-lane holds the other 16 j per tile

    // cross-wave tree reduction
    if (w >= 2) {
        float* Od = Ored[w-2];
        #pragma unroll
        for (int r = 0; r < 16; ++r) {
            int ii = (r & 3) + 8*(r >> 2) + 4*hi;
            Od[ii*48 + li] = accO0[r];
            if (li < 16) Od[ii*48 + 32 + li] = accO1[r];
        }
        if (lane < 32) Lred[w-2][lane] = rsum;
    }
    __syncthreads();
    if (w < 2) {
        const float* Od = Ored[w];
        #pragma unroll
        for (int r = 0; r < 16; ++r) {
            int ii = (r & 3) + 8*(r >> 2) + 4*hi;
            accO0[r] += Od[ii*48 + li];
            accO1[r] += Od[ii*48 + 32 + (li & 15)];
        }
        rsum += Lred[w][li];
    }
    __syncthreads();
    if (w == 1) {
        float* Od = Ored[0];
        #pragma unroll
        for (int r = 0; r < 16; ++r) {
            int ii = (r & 3) + 8*(r >> 2) + 4*hi;
            Od[ii*48 + li] = accO0[r];
            if (li < 16) Od[ii*48 + 32 + li] = accO1[r];
        }
        if (lane < 32) Lred[0][lane] = rsum;
    }
    __syncthreads();
    if (w == 0) {
        float* Od = Ored[0];
        #pragma unroll
        for (int r = 0; r < 16; ++r) {
            int ii = (r & 3) + 8*(r >> 2) + 4*hi;
            Od[ii*48 + li] += accO0[r];
            if (li < 16) Od[ii*48 + 32 + li] += accO1[r];
        }
        if (lane < 32) Lred[0][lane] += rsum;
    }
    __syncthreads();
    // all waves: normalize + coalesced int4 store of the 32x48 tile
    for (int c = t; c < 192; c += 256) {
        int r = c / 6, d8 = (c % 6)*8;
        float inv = 1.0f / Lred[0][r];
        const float* src = &Ored[0][r*48 + d8];
        short o[8];
        #pragma unroll
        for (int e = 0; e < 8; ++e) o[e] = f2b(src[e]*inv);
        *(int4*)(aob + ((size_t)(bi*SEQ) + i0 + r)*DM + hh*HD + d8) = *(const int4*)o;
    }
}

// ---------------- K4: MFMA GEMM out = aob @ Wout + b_out
__global__ __launch_bounds__(256) void k_out(const short* __restrict__ aob,
    const short* __restrict__ WT, const float* __restrict__ bias,
    void* __restrict__ out, const void* __restrict__ x)
{
    __shared__ __align__(16) short As[64*72];
    __shared__ __align__(16) short Bs[128*72];
    const int isf = detect_isf(x);
    const int t = threadIdx.x;
    const int w = t >> 6, lane = t & 63, L = lane & 15, quad = lane >> 4;
    const int mt = blockIdx.x / 3, nt = blockIdx.x % 3;
    const int row0 = mt*64, col0 = nt*128;
    const int wm = w & 1, wn = w >> 1;
    float4v acc[2][4] = {};
    for (int k0 = 0; k0 < DM; k0 += 64) {
        __syncthreads();
        for (int c = t; c < 512; c += 256) {
            int row = c >> 3, k8 = c & 7;
            *(int4*)(&As[row*72 + k8*8]) = *(const int4*)(aob + (size_t)(row0+row)*DM + k0 + k8*8);
        }
        for (int c = t; c < 1024; c += 256) {
            int row = c >> 3, k8 = c & 7;
            *(int4*)(&Bs[row*72 + k8*8]) = *(const int4*)(WT + (size_t)(col0+row)*DM + k0 + k8*8);
        }
        __syncthreads();
        #pragma unroll
        for (int kc = 0; kc < 2; ++kc) {
            short8 a0 = *(const short8*)(&As[(32*wm + L)*72 + kc*32 + quad*8]);
            short8 a1 = *(const short8*)(&As[(32*wm + 16 + L)*72 + kc*32 + quad*8]);
            #pragma unroll
            for (int ni = 0; ni < 4; ++ni) {
                short8 bf = *(const short8*)(&Bs[(64*wn + 16*ni + L)*72 + kc*32 + quad*8]);
                acc[0][ni] = __builtin_amdgcn_mfma_f32_16x16x32_bf16(a0, bf, acc[0][ni], 0, 0, 0);
                acc[1][ni] = __builtin_amdgcn_mfma_f32_16x16x32_bf16(a1, bf, acc[1][ni], 0, 0, 0);
            }
        }
    }
    #pragma unroll
    for (int mi = 0; mi < 2; ++mi) {
        #pragma unroll
        for (int ni = 0; ni < 4; ++ni) {
            int col_g = col0 + 64*wn + 16*ni + L;
            float bv = bias[col_g];
            #pragma unroll
            for (int r = 0; r < 4; ++r) {
                int row_g = row0 + 32*wm + 16*mi + quad*4 + r;
                size_t oi = (size_t)row_g*DM + col_g;
                float val = acc[mi][ni][r] + bv;
                if (isf) ((float*)out)[oi] = val;
                else     ((bf16*)out)[oi]  = __float2bfloat16(val);
            }
        }
    }
}

extern "C" void kernel_launch(void* const* d_in, const int* in_sizes, int n_in,
                              void* d_out, int out_size, void* d_ws, size_t ws_size,
                              hipStream_t stream) {
    const void* x      = d_in[0];
    const void* coords = d_in[1];
    const void* Wqkv   = d_in[2];
    const void* bqkv   = d_in[3];
    const void* Wdist  = d_in[4];
    const void* bdist  = d_in[5];
    const void* Wout   = d_in[6];
    const void* bout   = d_in[7];

    short* qg3   = (short*)d_ws;                       // 16*64*1536 = 1,572,864
    short* kg3   = qg3  + (size_t)1572864;
    short* vg3   = kg3  + (size_t)1572864;             // + 256 overread pad
    short* dist8 = vg3  + (size_t)1573120;             // 2*512*2048*4 = 8,388,608
    short* aob   = dist8 + (size_t)8388608;
    short* WqT   = aob  + (size_t)1572864;
    short* WoT   = WqT  + (size_t)442368;
    float* bqf   = (float*)(WoT + (size_t)147456);     // 16B-aligned
    float* bof   = bqf + QKVN;
    float* wdf   = bof + DM;
    float* bdf   = wdf + NH;

    k_wt<<<dim3(583), dim3(256), 0, stream>>>(x, Wqkv, Wout, bqkv, bout, Wdist, bdist,
                                              WqT, WoT, bqf, bof, wdf, bdf);
    k_qkv_dist<<<dim3(1088), dim3(256), 0, stream>>>(x, coords, WqT, bqf,
                                                     qg3, kg3, vg3, dist8);
    k_attn<<<dim3(1024), dim3(256), 0, stream>>>(qg3, kg3, vg3, dist8, wdf, bdf, aob);
    k_out<<<dim3(64*3), dim3(256), 0, stream>>>(aob, WoT, bof, d_out, x);
}